// Round 13
// baseline (792.049 us; speedup 1.0000x reference)
//
#include <hip/hip_runtime.h>
#include <hip/hip_bf16.h>

using short8 = __attribute__((ext_vector_type(8))) short;
using f32x4  = __attribute__((ext_vector_type(4))) float;

#define NN 2048
#define NC 8
static const size_t PLANE = (size_t)NN * NN;

__device__ __forceinline__ void gload16(const void* g, void* l) {
  __builtin_amdgcn_global_load_lds((const __attribute__((address_space(1))) unsigned int*)g,
                                   (__attribute__((address_space(3))) unsigned int*)l, 16, 0, 0);
}

// ---------------------------------------------------------------------------
// softmax over E=8 for 4 weight tensors [8c][8e] -> sw[4][8][8]
// ---------------------------------------------------------------------------
__global__ __launch_bounds__(256) void softmax_w_k(const float* __restrict__ w0, const float* __restrict__ w1,
                                                   const float* __restrict__ w2, const float* __restrict__ w3,
                                                   float* __restrict__ sw) {
  int t = threadIdx.x;
  const float* srcs[4] = {w0, w1, w2, w3};
  float v = srcs[t >> 6][t & 63];
  float m = v;
  #pragma unroll
  for (int d = 1; d < 8; d <<= 1) m = fmaxf(m, __shfl_xor(m, d, 8));
  float ex = __expf(v - m);
  float s = ex;
  #pragma unroll
  for (int d = 1; d < 8; d <<= 1) s += __shfl_xor(s, d, 8);
  sw[t] = ex / s;
}

// ---------------------------------------------------------------------------
// Fused gtconv: one pass over A [N,N,8] -> a (row-major), bT, c1T, (c2T).
// ---------------------------------------------------------------------------
template<int W4>
__global__ __launch_bounds__(512) void gtconv_fused(const float* __restrict__ A, const float* __restrict__ sw,
                                                    short* __restrict__ a, short* __restrict__ bT,
                                                    short* __restrict__ c1T, short* __restrict__ c2T) {
  __shared__ float tile[16384];     // 64 KB: [i 0..31][j 0..63][e 0..7] swizzled per 16B chunk
  __shared__ float swl[256];
  const int t = threadIdx.x;
  const int i0 = blockIdx.y * 32, j0 = blockIdx.x * 64;
  if (t < 256) swl[t] = sw[t];

  const float* Abase = A + ((size_t)i0 * NN + j0) * 8;
  #pragma unroll
  for (int q = 0; q < 8; q++) {
    const int d = q * 512 + t;
    const int s = (d & ~15) | ((d ^ (d >> 4)) & 15);
    const int row = s >> 7, fc = s & 127;
    gload16(Abase + (size_t)row * (NN * 8) + fc * 4, &tile[(q * 512 + (t & ~63)) * 4]);
  }
  asm volatile("s_waitcnt vmcnt(0)" ::: "memory");
  __syncthreads();

  // ---- row-major pass: tensor 0 ('a') ----
  {
    const int ch = t & 1, jg = (t >> 1) & 7, ii = t >> 4;
    const int sxx = (ii * 8 + jg) & 15;
    const int fb = ii * 128 + jg * 16;
    float acc[4][8];
    #pragma unroll
    for (int cc = 0; cc < 4; cc++)
      #pragma unroll
      for (int p = 0; p < 8; p++) acc[cc][p] = 0.f;
    #pragma unroll
    for (int p = 0; p < 8; p++) {
      const int k0 = p * 2;
      const float4 v0 = *reinterpret_cast<const float4*>(&tile[((fb & ~15) | (k0 ^ sxx)) * 4]);
      const float4 v1 = *reinterpret_cast<const float4*>(&tile[((fb & ~15) | ((k0 + 1) ^ sxx)) * 4]);
      const float e[8] = {v0.x, v0.y, v0.z, v0.w, v1.x, v1.y, v1.z, v1.w};
      #pragma unroll
      for (int cc = 0; cc < 4; cc++) {
        const int c = ch * 4 + cc;
        #pragma unroll
        for (int k = 0; k < 8; k++) acc[cc][p] += e[k] * swl[c * 8 + k];
      }
    }
    #pragma unroll
    for (int cc = 0; cc < 4; cc++) {
      const int c = ch * 4 + cc;
      short8 o;
      #pragma unroll
      for (int p = 0; p < 8; p++) {
        __hip_bfloat16 hb = __float2bfloat16(acc[cc][p]);
        o[p] = *reinterpret_cast<short*>(&hb);
      }
      *reinterpret_cast<short8*>(a + (size_t)c * PLANE + (size_t)(i0 + ii) * NN + j0 + jg * 8) = o;
    }
  }

  // ---- transposed passes: bT, c1T, (c2T) ----
  {
    const int ch = t & 1, ig = (t >> 1) & 3, jj = t >> 3;
    const int NT_OUT = W4 ? 3 : 2;
    short* outs[3] = {bT, c1T, c2T};
    #pragma unroll
    for (int T = 0; T < NT_OUT; T++) {
      short* outp = outs[T];
      const float* swt = &swl[(T + 1) * 64];
      float acc[4][8];
      #pragma unroll
      for (int cc = 0; cc < 4; cc++)
        #pragma unroll
        for (int p = 0; p < 8; p++) acc[cc][p] = 0.f;
      #pragma unroll
      for (int p = 0; p < 8; p++) {
        const int irow = ig * 8 + p;
        const int fb = irow * 128 + jj * 2;
        const int sxx = (irow * 8 + (jj >> 3)) & 15;
        const int k0 = fb & 15;
        const float4 v0 = *reinterpret_cast<const float4*>(&tile[((fb & ~15) | (k0 ^ sxx)) * 4]);
        const float4 v1 = *reinterpret_cast<const float4*>(&tile[((fb & ~15) | ((k0 + 1) ^ sxx)) * 4]);
        const float e[8] = {v0.x, v0.y, v0.z, v0.w, v1.x, v1.y, v1.z, v1.w};
        #pragma unroll
        for (int cc = 0; cc < 4; cc++) {
          const int c = ch * 4 + cc;
          #pragma unroll
          for (int k = 0; k < 8; k++) acc[cc][p] += e[k] * swt[c * 8 + k];
        }
      }
      #pragma unroll
      for (int cc = 0; cc < 4; cc++) {
        const int c = ch * 4 + cc;
        short8 o;
        #pragma unroll
        for (int p = 0; p < 8; p++) {
          __hip_bfloat16 hb = __float2bfloat16(acc[cc][p]);
          o[p] = *reinterpret_cast<short*>(&hb);
        }
        *reinterpret_cast<short8*>(outp + (size_t)c * PLANE + (size_t)(j0 + jj) * NN + i0 + ig * 8) = o;
      }
    }
  }
}

// fallback single transposed gtconv (c2T) when workspace is too small for 4 buffers
__global__ __launch_bounds__(256) void gtconv_one(const float* __restrict__ A, const float* __restrict__ sw,
                                                  __hip_bfloat16* __restrict__ oT) {
  __shared__ float Als[32][33][9];
  __shared__ float swl[8][8];
  int t = threadIdx.x;
  if (t < 64) swl[t >> 3][t & 7] = sw[t];
  int i0 = blockIdx.y * 32, j0 = blockIdx.x * 32;
  #pragma unroll
  for (int q = 0; q < 8; q++) {
    int fi = t + q * 256;
    int e4 = fi & 1, jj = (fi >> 1) & 31, ii = fi >> 6;
    const float4 v = *reinterpret_cast<const float4*>(A + (((size_t)(i0 + ii) * NN + (j0 + jj)) << 3) + e4 * 4);
    float* dst = &Als[ii][jj][e4 * 4];
    dst[0] = v.x; dst[1] = v.y; dst[2] = v.z; dst[3] = v.w;
  }
  __syncthreads();
  #pragma unroll
  for (int q = 0; q < 4; q++) {
    int pos = t + q * 256;
    int r = pos >> 5, s = pos & 31;
    float e[8];
    #pragma unroll
    for (int k = 0; k < 8; k++) e[k] = Als[s][r][k];
    size_t base = (size_t)(j0 + r) * NN + (i0 + s);
    #pragma unroll
    for (int c = 0; c < 8; c++) {
      float v1 = 0.f;
      #pragma unroll
      for (int k = 0; k < 8; k++) v1 += e[k] * swl[c][k];
      oT[(size_t)c * PLANE + base] = __float2bfloat16(v1);
    }
  }
}

// ---------------------------------------------------------------------------
// 256x256x64 bf16 GEMM, 8 waves (2Mx4N), SINGLE-buffered 64KB LDS ->
// 2 blocks/CU; inter-block overlap hides stage drain + read latency.
// Per tile: {STAGE; vmcnt(0); barrier; 24 ds_read + 64 MFMA; barrier}.
// global_load_lds linear dest + involution-swizzled source; XOR read swizzle
// (r8 16x16 pattern, measured conflict-free).
// ---------------------------------------------------------------------------
#define GBM 256
#define GBK 64
template<int CPB, int PARTIALS>
__global__ __launch_bounds__(512, 2) void gemm8(const short* __restrict__ Ag0, const short* __restrict__ Bg0,
                                                float* __restrict__ C, float* __restrict__ degp) {
  __shared__ short lds[32768];          // 64KB: A[0..16383] | B[16384..32767]
  __shared__ float colred[2][256];
  const int t = threadIdx.x;
  const int lane = t & 63, w = t >> 6;
  const int wr = w >> 2, wc = w & 3;    // 2 x 4 wave grid; wave tile 128(M) x 64(N)
  const int m0 = blockIdx.y * GBM, n0 = blockIdx.x * GBM;
  const short* Abase = Ag0 + (size_t)blockIdx.z * CPB * PLANE;
  const short* Bbase = Bg0 + (size_t)blockIdx.z * CPB * PLANE;
  const int NT = CPB * 32;

  const int lrow = t >> 3;              // 0..63 staging row within quarter
  const int lk8  = t & 7;               // 16B chunk id
  const int fr = lane & 15, fk = (lane >> 4) * 8;

  f32x4 acc[8][4] = {};

  // stage K-tile tt (linear LDS dest + involution-swizzled global source,
  // rule #21: LDS[row][ks] = G[row][ks ^ (row&7)*8]).
  auto STAGE = [&](int tt) {
    const int k0 = (tt & 31) * GBK;
    const short* Ag = Abase + (size_t)(tt >> 5) * PLANE;
    const short* Bg = Bbase + (size_t)(tt >> 5) * PLANE;
    #pragma unroll
    for (int q = 0; q < 4; q++) {
      const int row = q * 64 + lrow;
      const int ksrc = ((lk8 ^ (row & 7)) * 8);
      short* la = &lds[q * 4096 + w * 512];
      short* lb = &lds[16384 + q * 4096 + w * 512];
      gload16(Ag + (size_t)(m0 + row) * NN + k0 + ksrc, la);
      gload16(Bg + (size_t)(n0 + row) * NN + k0 + ksrc, lb);
    }
  };

  short8 aq[8][2], bq[4][2];            // 96 VGPR fragments

  for (int tt = 0; tt < NT; ++tt) {
    STAGE(tt);
    asm volatile("s_waitcnt vmcnt(0)" ::: "memory");   // own stage done
    __builtin_amdgcn_sched_barrier(0);
    __builtin_amdgcn_s_barrier();                      // tile complete in LDS
    __builtin_amdgcn_sched_barrier(0);

    #pragma unroll
    for (int m = 0; m < 8; m++) {
      const int row = wr * 128 + m * 16 + fr;
      const int sw8 = (row & 7) * 8;
      #pragma unroll
      for (int kx = 0; kx < 2; kx++)
        aq[m][kx] = *reinterpret_cast<const short8*>(&lds[row * 64 + ((kx * 32 + fk) ^ sw8)]);
    }
    #pragma unroll
    for (int n = 0; n < 4; n++) {
      const int row = wc * 64 + n * 16 + fr;
      const int sw8 = (row & 7) * 8;
      #pragma unroll
      for (int kx = 0; kx < 2; kx++)
        bq[n][kx] = *reinterpret_cast<const short8*>(&lds[16384 + row * 64 + ((kx * 32 + fk) ^ sw8)]);
    }
    __builtin_amdgcn_sched_barrier(0);
    __builtin_amdgcn_s_setprio(1);
    #pragma unroll
    for (int kx = 0; kx < 2; kx++)
      #pragma unroll
      for (int m = 0; m < 8; m++)
        #pragma unroll
        for (int n = 0; n < 4; n++)
          acc[m][n] = __builtin_amdgcn_mfma_f32_16x16x32_bf16(aq[m][kx], bq[n][kx], acc[m][n], 0, 0, 0);
    __builtin_amdgcn_s_setprio(0);
    __builtin_amdgcn_sched_barrier(0);
    __builtin_amdgcn_s_barrier();                      // consumption done -> next STAGE safe
    __builtin_amdgcn_sched_barrier(0);
  }

  float* Cg = C + (size_t)blockIdx.z * PLANE;
  const int orow = (lane >> 4) * 4, ocol = lane & 15;
  #pragma unroll
  for (int m = 0; m < 8; m++)
    #pragma unroll
    for (int n = 0; n < 4; n++) {
      const int gr = m0 + wr * 128 + m * 16 + orow;
      const int gc = n0 + wc * 64 + n * 16 + ocol;
      #pragma unroll
      for (int j = 0; j < 4; j++)
        Cg[(size_t)(gr + j) * NN + gc] = acc[m][n][j];
    }

  if (PARTIALS) {
    #pragma unroll
    for (int n = 0; n < 4; n++) {
      float s = 0.f;
      #pragma unroll
      for (int m = 0; m < 8; m++)
        #pragma unroll
        for (int j = 0; j < 4; j++) s += acc[m][n][j];
      s += __shfl_xor(s, 16);
      s += __shfl_xor(s, 32);
      if (lane < 16) colred[wr][wc * 64 + n * 16 + lane] = s;
    }
    __syncthreads();
    if (t < 256) {
      float s = colred[0][t] + colred[1][t];
      degp[((size_t)blockIdx.z * 8 + blockIdx.y) * NN + n0 + t] = s;
    }
  }
}

// ---------------------------------------------------------------------------
// deg[c][j] = sum of 8 block partials - diag; invert
// ---------------------------------------------------------------------------
__global__ __launch_bounds__(256) void reduce_inv(const float* __restrict__ degp, const float* __restrict__ H,
                                                  float* __restrict__ deginv) {
  int idx = blockIdx.x * 256 + threadIdx.x;   // 8*2048
  int c = idx >> 11, j = idx & (NN - 1);
  float s = 0.f;
  #pragma unroll
  for (int tb = 0; tb < 8; tb++) s += degp[((size_t)c * 8 + tb) * NN + j];
  s -= H[(size_t)c * PLANE + (size_t)j * NN + j];
  deginv[idx] = (s == 0.f) ? 0.f : 1.f / s;
}

// ---------------------------------------------------------------------------
// Hn(bf16) = (i==j ? 0 : H * deginv[c][j]); 8 elems/thread
// ---------------------------------------------------------------------------
__global__ __launch_bounds__(256) void normalize_cast(const float* __restrict__ H, const float* __restrict__ deginv,
                                                      short* __restrict__ Hn) {
  size_t idx = (size_t)blockIdx.x * 256 + threadIdx.x;
  size_t e0 = idx * 8;
  int c = (int)(e0 >> 22);
  size_t rem = e0 & (PLANE - 1);
  int i = (int)(rem >> 11), j0 = (int)(rem & (NN - 1));
  const float4 h0 = *reinterpret_cast<const float4*>(H + e0);
  const float4 h1 = *reinterpret_cast<const float4*>(H + e0 + 4);
  const float4 d0 = *reinterpret_cast<const float4*>(deginv + c * NN + j0);
  const float4 d1 = *reinterpret_cast<const float4*>(deginv + c * NN + j0 + 4);
  float v[8] = {h0.x * d0.x, h0.y * d0.y, h0.z * d0.z, h0.w * d0.w,
                h1.x * d1.x, h1.y * d1.y, h1.z * d1.z, h1.w * d1.w};
  int dd = i - j0;
  if (dd >= 0 && dd < 8) v[dd] = 0.f;
  short8 o;
  #pragma unroll
  for (int k = 0; k < 8; k++) {
    __hip_bfloat16 hb = __float2bfloat16(v[k]);
    o[k] = *reinterpret_cast<short*>(&hb);
  }
  *reinterpret_cast<short8*>(Hn + e0) = o;
}

// ---------------------------------------------------------------------------
// out[i][j] = (1/16) * sum_{p<8} (Mp[i][j] + Mp[j][i])
// ---------------------------------------------------------------------------
__global__ __launch_bounds__(256) void final_sym8(const float* __restrict__ M, float* __restrict__ out) {
  __shared__ float tl[64][65];
  int t = threadIdx.x;
  int i0 = blockIdx.y * 64, j0 = blockIdx.x * 64;
  int r0 = t >> 6, cl = t & 63;
  float acc[16];
  #pragma unroll
  for (int q = 0; q < 16; q++) acc[q] = 0.f;
  for (int p = 0; p < 8; p++) {
    const float* Mp = M + (size_t)p * PLANE;
    __syncthreads();
    #pragma unroll
    for (int q = 0; q < 16; q++) {
      int rr = r0 + q * 4;
      tl[rr][cl] = Mp[(size_t)(j0 + rr) * NN + i0 + cl];
    }
    __syncthreads();
    #pragma unroll
    for (int q = 0; q < 16; q++) {
      int rr = r0 + q * 4;
      acc[q] += Mp[(size_t)(i0 + rr) * NN + j0 + cl] + tl[cl][rr];
    }
  }
  #pragma unroll
  for (int q = 0; q < 16; q++) {
    int rr = r0 + q * 4;
    out[(size_t)(i0 + rr) * NN + j0 + cl] = acc[q] * (1.0f / 16.0f);
  }
}

// ---------------------------------------------------------------------------
extern "C" void kernel_launch(void* const* d_in, const int* in_sizes, int n_in,
                              void* d_out, int out_size, void* d_ws, size_t ws_size,
                              hipStream_t stream) {
  const float* A    = (const float*)d_in[0];
  const float* w1_0 = (const float*)d_in[1];
  const float* w2_0 = (const float*)d_in[2];
  const float* w_1  = (const float*)d_in[3];
  const float* w_2  = (const float*)d_in[4];
  float* out = (float*)d_out;

  char* w = (char*)d_ws;
  float* sw     = (float*)w;                                  // 256 f
  float* degp   = (float*)(w + (1 << 17));                    // 8*8*2048 f
  float* deginv = (float*)(w + (1 << 17) + (1 << 21));        // 16K f
  const size_t BSZ = (size_t)NC * PLANE * sizeof(short);      // 64MB per bf16 stack
  short* B0 = (short*)(w + (4u << 20));                       // a  / Hn / Hn2
  short* B1 = (short*)((char*)B0 + BSZ);                      // bT (/ c2T in fallback)
  short* B2 = (short*)((char*)B1 + BSZ);                      // c1T
  const size_t HSZ = (size_t)NC * PLANE * sizeof(float);      // 128MB fp32 H
  const size_t need4 = (4u << 20) + 4 * BSZ + HSZ;
  const bool fused4 = ws_size >= need4;
  short* B3 = (short*)((char*)B2 + BSZ);                      // c2T (fused path only)
  float* HH = fused4 ? (float*)((char*)B3 + BSZ) : (float*)((char*)B2 + BSZ);

  dim3 blk(256), blkg(512);
  dim3 gfuse(NN / 64, NN / 32);
  dim3 gconv(64, 64);
  dim3 ggemm(8, 8, 8);

  softmax_w_k<<<1, blk, 0, stream>>>(w1_0, w2_0, w_1, w_2, sw);
  if (fused4) {
    gtconv_fused<1><<<gfuse, blkg, 0, stream>>>(A, sw, B0, B1, B2, B3);
  } else {
    gtconv_fused<0><<<gfuse, blkg, 0, stream>>>(A, sw, B0, B1, B2, B3);
  }

  gemm8<1, 1><<<ggemm, blkg, 0, stream>>>(B0, B1, HH, degp);          // H1 = a @ b, + col partials
  reduce_inv<<<64, blk, 0, stream>>>(degp, HH, deginv);
  normalize_cast<<<16384, blk, 0, stream>>>(HH, deginv, B0);          // Hn -> B0
  if (!fused4) {
    gtconv_one<<<gconv, blk, 0, stream>>>(A, sw + 192, (__hip_bfloat16*)B1);  // c2T -> B1
  }

  gemm8<1, 1><<<ggemm, blkg, 0, stream>>>(B0, B2, HH, degp);          // H2 = Hn @ c1, + partials
  reduce_inv<<<64, blk, 0, stream>>>(degp, HH, deginv);
  normalize_cast<<<16384, blk, 0, stream>>>(HH, deginv, B0);          // Hn2 -> B0

  short* Bc2 = fused4 ? B3 : B1;
  gemm8<1, 0><<<ggemm, blkg, 0, stream>>>(B0, Bc2, HH, degp);         // M[z] = Hn2[z] @ c2[z]
  final_sym8<<<dim3(32, 32), blk, 0, stream>>>(HH, out);
}

// Round 14
// 646.679 us; speedup vs baseline: 1.2248x; 1.2248x over previous
//
#include <hip/hip_runtime.h>
#include <hip/hip_bf16.h>

using short8 = __attribute__((ext_vector_type(8))) short;
using f32x4  = __attribute__((ext_vector_type(4))) float;

#define NN 2048
#define NC 8
static const size_t PLANE = (size_t)NN * NN;

__device__ __forceinline__ void gload16(const void* g, void* l) {
  __builtin_amdgcn_global_load_lds((const __attribute__((address_space(1))) unsigned int*)g,
                                   (__attribute__((address_space(3))) unsigned int*)l, 16, 0, 0);
}

// ---------------------------------------------------------------------------
// softmax over E=8 for 4 weight tensors [8c][8e] -> sw[4][8][8]
// ---------------------------------------------------------------------------
__global__ __launch_bounds__(256) void softmax_w_k(const float* __restrict__ w0, const float* __restrict__ w1,
                                                   const float* __restrict__ w2, const float* __restrict__ w3,
                                                   float* __restrict__ sw) {
  int t = threadIdx.x;
  const float* srcs[4] = {w0, w1, w2, w3};
  float v = srcs[t >> 6][t & 63];
  float m = v;
  #pragma unroll
  for (int d = 1; d < 8; d <<= 1) m = fmaxf(m, __shfl_xor(m, d, 8));
  float ex = __expf(v - m);
  float s = ex;
  #pragma unroll
  for (int d = 1; d < 8; d <<= 1) s += __shfl_xor(s, d, 8);
  sw[t] = ex / s;
}

// ---------------------------------------------------------------------------
// Fused gtconv: one pass over A [N,N,8] -> a (row-major), bT, c1T, (c2T).
// ---------------------------------------------------------------------------
template<int W4>
__global__ __launch_bounds__(512) void gtconv_fused(const float* __restrict__ A, const float* __restrict__ sw,
                                                    short* __restrict__ a, short* __restrict__ bT,
                                                    short* __restrict__ c1T, short* __restrict__ c2T) {
  __shared__ float tile[16384];     // 64 KB: [i 0..31][j 0..63][e 0..7] swizzled per 16B chunk
  __shared__ float swl[256];
  const int t = threadIdx.x;
  const int i0 = blockIdx.y * 32, j0 = blockIdx.x * 64;
  if (t < 256) swl[t] = sw[t];

  const float* Abase = A + ((size_t)i0 * NN + j0) * 8;
  #pragma unroll
  for (int q = 0; q < 8; q++) {
    const int d = q * 512 + t;
    const int s = (d & ~15) | ((d ^ (d >> 4)) & 15);
    const int row = s >> 7, fc = s & 127;
    gload16(Abase + (size_t)row * (NN * 8) + fc * 4, &tile[(q * 512 + (t & ~63)) * 4]);
  }
  asm volatile("s_waitcnt vmcnt(0)" ::: "memory");
  __syncthreads();

  // ---- row-major pass: tensor 0 ('a') ----
  {
    const int ch = t & 1, jg = (t >> 1) & 7, ii = t >> 4;
    const int sxx = (ii * 8 + jg) & 15;
    const int fb = ii * 128 + jg * 16;
    float acc[4][8];
    #pragma unroll
    for (int cc = 0; cc < 4; cc++)
      #pragma unroll
      for (int p = 0; p < 8; p++) acc[cc][p] = 0.f;
    #pragma unroll
    for (int p = 0; p < 8; p++) {
      const int k0 = p * 2;
      const float4 v0 = *reinterpret_cast<const float4*>(&tile[((fb & ~15) | (k0 ^ sxx)) * 4]);
      const float4 v1 = *reinterpret_cast<const float4*>(&tile[((fb & ~15) | ((k0 + 1) ^ sxx)) * 4]);
      const float e[8] = {v0.x, v0.y, v0.z, v0.w, v1.x, v1.y, v1.z, v1.w};
      #pragma unroll
      for (int cc = 0; cc < 4; cc++) {
        const int c = ch * 4 + cc;
        #pragma unroll
        for (int k = 0; k < 8; k++) acc[cc][p] += e[k] * swl[c * 8 + k];
      }
    }
    #pragma unroll
    for (int cc = 0; cc < 4; cc++) {
      const int c = ch * 4 + cc;
      short8 o;
      #pragma unroll
      for (int p = 0; p < 8; p++) {
        __hip_bfloat16 hb = __float2bfloat16(acc[cc][p]);
        o[p] = *reinterpret_cast<short*>(&hb);
      }
      *reinterpret_cast<short8*>(a + (size_t)c * PLANE + (size_t)(i0 + ii) * NN + j0 + jg * 8) = o;
    }
  }

  // ---- transposed passes: bT, c1T, (c2T) ----
  {
    const int ch = t & 1, ig = (t >> 1) & 3, jj = t >> 3;
    const int NT_OUT = W4 ? 3 : 2;
    short* outs[3] = {bT, c1T, c2T};
    #pragma unroll
    for (int T = 0; T < NT_OUT; T++) {
      short* outp = outs[T];
      const float* swt = &swl[(T + 1) * 64];
      float acc[4][8];
      #pragma unroll
      for (int cc = 0; cc < 4; cc++)
        #pragma unroll
        for (int p = 0; p < 8; p++) acc[cc][p] = 0.f;
      #pragma unroll
      for (int p = 0; p < 8; p++) {
        const int irow = ig * 8 + p;
        const int fb = irow * 128 + jj * 2;
        const int sxx = (irow * 8 + (jj >> 3)) & 15;
        const int k0 = fb & 15;
        const float4 v0 = *reinterpret_cast<const float4*>(&tile[((fb & ~15) | (k0 ^ sxx)) * 4]);
        const float4 v1 = *reinterpret_cast<const float4*>(&tile[((fb & ~15) | ((k0 + 1) ^ sxx)) * 4]);
        const float e[8] = {v0.x, v0.y, v0.z, v0.w, v1.x, v1.y, v1.z, v1.w};
        #pragma unroll
        for (int cc = 0; cc < 4; cc++) {
          const int c = ch * 4 + cc;
          #pragma unroll
          for (int k = 0; k < 8; k++) acc[cc][p] += e[k] * swt[c * 8 + k];
        }
      }
      #pragma unroll
      for (int cc = 0; cc < 4; cc++) {
        const int c = ch * 4 + cc;
        short8 o;
        #pragma unroll
        for (int p = 0; p < 8; p++) {
          __hip_bfloat16 hb = __float2bfloat16(acc[cc][p]);
          o[p] = *reinterpret_cast<short*>(&hb);
        }
        *reinterpret_cast<short8*>(outp + (size_t)c * PLANE + (size_t)(j0 + jj) * NN + i0 + ig * 8) = o;
      }
    }
  }
}

// fallback single transposed gtconv (c2T) when workspace is too small for 4 buffers
__global__ __launch_bounds__(256) void gtconv_one(const float* __restrict__ A, const float* __restrict__ sw,
                                                  __hip_bfloat16* __restrict__ oT) {
  __shared__ float Als[32][33][9];
  __shared__ float swl[8][8];
  int t = threadIdx.x;
  if (t < 64) swl[t >> 3][t & 7] = sw[t];
  int i0 = blockIdx.y * 32, j0 = blockIdx.x * 32;
  #pragma unroll
  for (int q = 0; q < 8; q++) {
    int fi = t + q * 256;
    int e4 = fi & 1, jj = (fi >> 1) & 31, ii = fi >> 6;
    const float4 v = *reinterpret_cast<const float4*>(A + (((size_t)(i0 + ii) * NN + (j0 + jj)) << 3) + e4 * 4);
    float* dst = &Als[ii][jj][e4 * 4];
    dst[0] = v.x; dst[1] = v.y; dst[2] = v.z; dst[3] = v.w;
  }
  __syncthreads();
  #pragma unroll
  for (int q = 0; q < 4; q++) {
    int pos = t + q * 256;
    int r = pos >> 5, s = pos & 31;
    float e[8];
    #pragma unroll
    for (int k = 0; k < 8; k++) e[k] = Als[s][r][k];
    size_t base = (size_t)(j0 + r) * NN + (i0 + s);
    #pragma unroll
    for (int c = 0; c < 8; c++) {
      float v1 = 0.f;
      #pragma unroll
      for (int k = 0; k < 8; k++) v1 += e[k] * swl[c][k];
      oT[(size_t)c * PLANE + base] = __float2bfloat16(v1);
    }
  }
}

// ---------------------------------------------------------------------------
// m97-faithful 128x128x64 bf16 GEMM: 4 waves (2x2, wave tile 64x64),
// single-buffer 32KB LDS, global_load_lds w16 (linear dest + involution-
// swizzled source; XOR read swizzle -> 0 conflicts), simple 2-barrier loop.
// acc 64 AGPR + per-kx frags 32 VGPR => ~164 regs => 3 blocks/CU
// (launch_bounds(256,3)); co-resident blocks hide stage drain (m114).
// ---------------------------------------------------------------------------
#define GBM 128
#define GBK 64
template<int CPB, int PARTIALS>
__global__ __launch_bounds__(256, 3) void gemm8(const short* __restrict__ Ag0, const short* __restrict__ Bg0,
                                                float* __restrict__ C, float* __restrict__ degp) {
  __shared__ short lds[16384];          // 32KB: A [0..8191] | B [8192..16383]
  __shared__ float colred[2][128];
  const int t = threadIdx.x;
  const int lane = t & 63, w = t >> 6;
  const int wr = w >> 1, wc = w & 1;    // 2 x 2 wave grid; wave tile 64(M) x 64(N)
  const int m0 = blockIdx.y * GBM, n0 = blockIdx.x * GBM;
  const short* Abase = Ag0 + (size_t)blockIdx.z * CPB * PLANE;
  const short* Bbase = Bg0 + (size_t)blockIdx.z * CPB * PLANE;
  const int NT = CPB * 32;

  const int lrow = t >> 3;              // 0..31 staging row within quarter
  const int lk8  = t & 7;               // 16B chunk id
  const int fr = lane & 15, fk = (lane >> 4) * 8;

  f32x4 acc[4][4] = {};

  // stage K-tile tt (linear LDS dest + involution-swizzled global source,
  // rule #21: LDS[row][ks] = G[row][ks ^ (row&7)*8]).
  auto STAGE = [&](int tt) {
    const int k0 = (tt & 31) * GBK;
    const short* Ag = Abase + (size_t)(tt >> 5) * PLANE;
    const short* Bg = Bbase + (size_t)(tt >> 5) * PLANE;
    #pragma unroll
    for (int q = 0; q < 4; q++) {
      const int row = q * 32 + lrow;
      const int ksrc = ((lk8 ^ (row & 7)) * 8);
      short* la = &lds[q * 2048 + w * 512];
      short* lb = &lds[8192 + q * 2048 + w * 512];
      gload16(Ag + (size_t)(m0 + row) * NN + k0 + ksrc, la);
      gload16(Bg + (size_t)(n0 + row) * NN + k0 + ksrc, lb);
    }
  };

  for (int tt = 0; tt < NT; ++tt) {
    STAGE(tt);
    asm volatile("s_waitcnt vmcnt(0)" ::: "memory");
    __builtin_amdgcn_sched_barrier(0);
    __builtin_amdgcn_s_barrier();                      // tile complete in LDS
    __builtin_amdgcn_sched_barrier(0);

    #pragma unroll
    for (int kx = 0; kx < 2; kx++) {
      short8 af[4], bf[4];                             // 32 VGPR live (m97 size)
      #pragma unroll
      for (int m = 0; m < 4; m++) {
        const int row = wr * 64 + m * 16 + fr;
        const int sw8 = (row & 7) * 8;
        af[m] = *reinterpret_cast<const short8*>(&lds[row * 64 + ((kx * 32 + fk) ^ sw8)]);
      }
      #pragma unroll
      for (int n = 0; n < 4; n++) {
        const int row = wc * 64 + n * 16 + fr;
        const int sw8 = (row & 7) * 8;
        bf[n] = *reinterpret_cast<const short8*>(&lds[8192 + row * 64 + ((kx * 32 + fk) ^ sw8)]);
      }
      __builtin_amdgcn_s_setprio(1);
      #pragma unroll
      for (int m = 0; m < 4; m++)
        #pragma unroll
        for (int n = 0; n < 4; n++)
          acc[m][n] = __builtin_amdgcn_mfma_f32_16x16x32_bf16(af[m], bf[n], acc[m][n], 0, 0, 0);
      __builtin_amdgcn_s_setprio(0);
    }
    __builtin_amdgcn_sched_barrier(0);
    __builtin_amdgcn_s_barrier();                      // consumption done -> next STAGE safe
    __builtin_amdgcn_sched_barrier(0);
  }

  float* Cg = C + (size_t)blockIdx.z * PLANE;
  const int orow = (lane >> 4) * 4, ocol = lane & 15;
  #pragma unroll
  for (int m = 0; m < 4; m++)
    #pragma unroll
    for (int n = 0; n < 4; n++) {
      const int gr = m0 + wr * 64 + m * 16 + orow;
      const int gc = n0 + wc * 64 + n * 16 + ocol;
      #pragma unroll
      for (int j = 0; j < 4; j++)
        Cg[(size_t)(gr + j) * NN + gc] = acc[m][n][j];
    }

  if (PARTIALS) {
    #pragma unroll
    for (int n = 0; n < 4; n++) {
      float s = 0.f;
      #pragma unroll
      for (int m = 0; m < 4; m++)
        #pragma unroll
        for (int j = 0; j < 4; j++) s += acc[m][n][j];
      s += __shfl_xor(s, 16);
      s += __shfl_xor(s, 32);
      if (lane < 16) colred[wr][wc * 64 + n * 16 + lane] = s;
    }
    __syncthreads();
    if (t < 128) {
      float s = colred[0][t] + colred[1][t];
      degp[((size_t)blockIdx.z * 16 + blockIdx.y) * NN + n0 + t] = s;
    }
  }
}

// ---------------------------------------------------------------------------
// deg[c][j] = sum of 16 block partials - diag; invert
// ---------------------------------------------------------------------------
__global__ __launch_bounds__(256) void reduce_inv(const float* __restrict__ degp, const float* __restrict__ H,
                                                  float* __restrict__ deginv) {
  int idx = blockIdx.x * 256 + threadIdx.x;   // 8*2048
  int c = idx >> 11, j = idx & (NN - 1);
  float s = 0.f;
  #pragma unroll
  for (int tb = 0; tb < 16; tb++) s += degp[((size_t)c * 16 + tb) * NN + j];
  s -= H[(size_t)c * PLANE + (size_t)j * NN + j];
  deginv[idx] = (s == 0.f) ? 0.f : 1.f / s;
}

// ---------------------------------------------------------------------------
// Hn(bf16) = (i==j ? 0 : H * deginv[c][j]); 8 elems/thread
// ---------------------------------------------------------------------------
__global__ __launch_bounds__(256) void normalize_cast(const float* __restrict__ H, const float* __restrict__ deginv,
                                                      short* __restrict__ Hn) {
  size_t idx = (size_t)blockIdx.x * 256 + threadIdx.x;
  size_t e0 = idx * 8;
  int c = (int)(e0 >> 22);
  size_t rem = e0 & (PLANE - 1);
  int i = (int)(rem >> 11), j0 = (int)(rem & (NN - 1));
  const float4 h0 = *reinterpret_cast<const float4*>(H + e0);
  const float4 h1 = *reinterpret_cast<const float4*>(H + e0 + 4);
  const float4 d0 = *reinterpret_cast<const float4*>(deginv + c * NN + j0);
  const float4 d1 = *reinterpret_cast<const float4*>(deginv + c * NN + j0 + 4);
  float v[8] = {h0.x * d0.x, h0.y * d0.y, h0.z * d0.z, h0.w * d0.w,
                h1.x * d1.x, h1.y * d1.y, h1.z * d1.z, h1.w * d1.w};
  int dd = i - j0;
  if (dd >= 0 && dd < 8) v[dd] = 0.f;
  short8 o;
  #pragma unroll
  for (int k = 0; k < 8; k++) {
    __hip_bfloat16 hb = __float2bfloat16(v[k]);
    o[k] = *reinterpret_cast<short*>(&hb);
  }
  *reinterpret_cast<short8*>(Hn + e0) = o;
}

// ---------------------------------------------------------------------------
// out[i][j] = (1/16) * sum_{p<4} (Mp[i][j] + Mp[j][i])
// ---------------------------------------------------------------------------
__global__ __launch_bounds__(256) void final_sym4(const float* __restrict__ M, float* __restrict__ out) {
  __shared__ float tl[64][65];
  int t = threadIdx.x;
  int i0 = blockIdx.y * 64, j0 = blockIdx.x * 64;
  int r0 = t >> 6, cl = t & 63;
  float acc[16];
  #pragma unroll
  for (int q = 0; q < 16; q++) acc[q] = 0.f;
  for (int p = 0; p < 4; p++) {
    const float* Mp = M + (size_t)p * PLANE;
    __syncthreads();
    #pragma unroll
    for (int q = 0; q < 16; q++) {
      int rr = r0 + q * 4;
      tl[rr][cl] = Mp[(size_t)(j0 + rr) * NN + i0 + cl];
    }
    __syncthreads();
    #pragma unroll
    for (int q = 0; q < 16; q++) {
      int rr = r0 + q * 4;
      acc[q] += Mp[(size_t)(i0 + rr) * NN + j0 + cl] + tl[cl][rr];
    }
  }
  #pragma unroll
  for (int q = 0; q < 16; q++) {
    int rr = r0 + q * 4;
    out[(size_t)(i0 + rr) * NN + j0 + cl] = acc[q] * (1.0f / 16.0f);
  }
}

// ---------------------------------------------------------------------------
extern "C" void kernel_launch(void* const* d_in, const int* in_sizes, int n_in,
                              void* d_out, int out_size, void* d_ws, size_t ws_size,
                              hipStream_t stream) {
  const float* A    = (const float*)d_in[0];
  const float* w1_0 = (const float*)d_in[1];
  const float* w2_0 = (const float*)d_in[2];
  const float* w_1  = (const float*)d_in[3];
  const float* w_2  = (const float*)d_in[4];
  float* out = (float*)d_out;

  char* w = (char*)d_ws;
  float* sw     = (float*)w;                                  // 256 f
  float* degp   = (float*)(w + (1 << 17));                    // 8*16*2048 f = 1MB
  float* deginv = (float*)(w + (1 << 17) + (1 << 21));        // 16K f
  const size_t BSZ = (size_t)NC * PLANE * sizeof(short);      // 64MB per bf16 stack
  short* B0 = (short*)(w + (4u << 20));                       // a  / Hn / Hn2
  short* B1 = (short*)((char*)B0 + BSZ);                      // bT (/ c2T in fallback)
  short* B2 = (short*)((char*)B1 + BSZ);                      // c1T
  const size_t HSZ = (size_t)NC * PLANE * sizeof(float);      // 128MB fp32 H
  const size_t need4 = (4u << 20) + 4 * BSZ + HSZ;
  const bool fused4 = ws_size >= need4;
  short* B3 = (short*)((char*)B2 + BSZ);                      // c2T (fused path only)
  float* HH = fused4 ? (float*)((char*)B3 + BSZ) : (float*)((char*)B2 + BSZ);

  dim3 blk(256), blkg(512);
  dim3 gfuse(NN / 64, NN / 32);
  dim3 gconv(64, 64);
  dim3 ggemm(16, 16, 8);
  dim3 ggemm4(16, 16, 4);

  softmax_w_k<<<1, blk, 0, stream>>>(w1_0, w2_0, w_1, w_2, sw);
  if (fused4) {
    gtconv_fused<1><<<gfuse, blkg, 0, stream>>>(A, sw, B0, B1, B2, B3);
  } else {
    gtconv_fused<0><<<gfuse, blkg, 0, stream>>>(A, sw, B0, B1, B2, B3);
  }

  gemm8<1, 1><<<ggemm, blk, 0, stream>>>(B0, B1, HH, degp);           // H1 = a @ b, + col partials
  reduce_inv<<<64, blk, 0, stream>>>(degp, HH, deginv);
  normalize_cast<<<16384, blk, 0, stream>>>(HH, deginv, B0);          // Hn -> B0
  if (!fused4) {
    gtconv_one<<<gconv, blk, 0, stream>>>(A, sw + 192, (__hip_bfloat16*)B1);  // c2T -> B1
  }

  gemm8<1, 1><<<ggemm, blk, 0, stream>>>(B0, B2, HH, degp);           // H2 = Hn @ c1, + partials
  reduce_inv<<<64, blk, 0, stream>>>(degp, HH, deginv);
  normalize_cast<<<16384, blk, 0, stream>>>(HH, deginv, B0);          // Hn2 -> B0

  short* Bc2 = fused4 ? B3 : B1;
  gemm8<2, 0><<<ggemm4, blk, 0, stream>>>(B0, Bc2, HH, degp);         // M[z] = sum_{c in pair z} Hn2[c] @ c2[c]
  final_sym4<<<dim3(32, 32), blk, 0, stream>>>(HH, out);
}

// Round 15
// 591.829 us; speedup vs baseline: 1.3383x; 1.0927x over previous
//
#include <hip/hip_runtime.h>
#include <hip/hip_bf16.h>

using short8 = __attribute__((ext_vector_type(8))) short;
using f32x4  = __attribute__((ext_vector_type(4))) float;

#define NN 2048
#define NC 8
static const size_t PLANE = (size_t)NN * NN;

__device__ __forceinline__ void gload16(const void* g, void* l) {
  __builtin_amdgcn_global_load_lds((const __attribute__((address_space(1))) unsigned int*)g,
                                   (__attribute__((address_space(3))) unsigned int*)l, 16, 0, 0);
}

__device__ __forceinline__ float b2f(short s) {
  unsigned int u = ((unsigned int)(unsigned short)s) << 16;
  float f; __builtin_memcpy(&f, &u, 4); return f;
}
__device__ __forceinline__ short f2b(float f) {
  __hip_bfloat16 hb = __float2bfloat16(f);
  return *reinterpret_cast<short*>(&hb);
}

// ---------------------------------------------------------------------------
// softmax over E=8 for 4 weight tensors [8c][8e] -> sw[4][8][8]
// ---------------------------------------------------------------------------
__global__ __launch_bounds__(256) void softmax_w_k(const float* __restrict__ w0, const float* __restrict__ w1,
                                                   const float* __restrict__ w2, const float* __restrict__ w3,
                                                   float* __restrict__ sw) {
  int t = threadIdx.x;
  const float* srcs[4] = {w0, w1, w2, w3};
  float v = srcs[t >> 6][t & 63];
  float m = v;
  #pragma unroll
  for (int d = 1; d < 8; d <<= 1) m = fmaxf(m, __shfl_xor(m, d, 8));
  float ex = __expf(v - m);
  float s = ex;
  #pragma unroll
  for (int d = 1; d < 8; d <<= 1) s += __shfl_xor(s, d, 8);
  sw[t] = ex / s;
}

// ---------------------------------------------------------------------------
// Fused gtconv: one pass over A [N,N,8] -> a (row-major), bT, c1T, (c2T).
// ---------------------------------------------------------------------------
template<int W4>
__global__ __launch_bounds__(512) void gtconv_fused(const float* __restrict__ A, const float* __restrict__ sw,
                                                    short* __restrict__ a, short* __restrict__ bT,
                                                    short* __restrict__ c1T, short* __restrict__ c2T) {
  __shared__ float tile[16384];     // 64 KB: [i 0..31][j 0..63][e 0..7] swizzled per 16B chunk
  __shared__ float swl[256];
  const int t = threadIdx.x;
  const int i0 = blockIdx.y * 32, j0 = blockIdx.x * 64;
  if (t < 256) swl[t] = sw[t];

  const float* Abase = A + ((size_t)i0 * NN + j0) * 8;
  #pragma unroll
  for (int q = 0; q < 8; q++) {
    const int d = q * 512 + t;
    const int s = (d & ~15) | ((d ^ (d >> 4)) & 15);
    const int row = s >> 7, fc = s & 127;
    gload16(Abase + (size_t)row * (NN * 8) + fc * 4, &tile[(q * 512 + (t & ~63)) * 4]);
  }
  asm volatile("s_waitcnt vmcnt(0)" ::: "memory");
  __syncthreads();

  // ---- row-major pass: tensor 0 ('a') ----
  {
    const int ch = t & 1, jg = (t >> 1) & 7, ii = t >> 4;
    const int sxx = (ii * 8 + jg) & 15;
    const int fb = ii * 128 + jg * 16;
    float acc[4][8];
    #pragma unroll
    for (int cc = 0; cc < 4; cc++)
      #pragma unroll
      for (int p = 0; p < 8; p++) acc[cc][p] = 0.f;
    #pragma unroll
    for (int p = 0; p < 8; p++) {
      const int k0 = p * 2;
      const float4 v0 = *reinterpret_cast<const float4*>(&tile[((fb & ~15) | (k0 ^ sxx)) * 4]);
      const float4 v1 = *reinterpret_cast<const float4*>(&tile[((fb & ~15) | ((k0 + 1) ^ sxx)) * 4]);
      const float e[8] = {v0.x, v0.y, v0.z, v0.w, v1.x, v1.y, v1.z, v1.w};
      #pragma unroll
      for (int cc = 0; cc < 4; cc++) {
        const int c = ch * 4 + cc;
        #pragma unroll
        for (int k = 0; k < 8; k++) acc[cc][p] += e[k] * swl[c * 8 + k];
      }
    }
    #pragma unroll
    for (int cc = 0; cc < 4; cc++) {
      const int c = ch * 4 + cc;
      short8 o;
      #pragma unroll
      for (int p = 0; p < 8; p++) o[p] = f2b(acc[cc][p]);
      *reinterpret_cast<short8*>(a + (size_t)c * PLANE + (size_t)(i0 + ii) * NN + j0 + jg * 8) = o;
    }
  }

  // ---- transposed passes: bT, c1T, (c2T) ----
  {
    const int ch = t & 1, ig = (t >> 1) & 3, jj = t >> 3;
    const int NT_OUT = W4 ? 3 : 2;
    short* outs[3] = {bT, c1T, c2T};
    #pragma unroll
    for (int T = 0; T < NT_OUT; T++) {
      short* outp = outs[T];
      const float* swt = &swl[(T + 1) * 64];
      float acc[4][8];
      #pragma unroll
      for (int cc = 0; cc < 4; cc++)
        #pragma unroll
        for (int p = 0; p < 8; p++) acc[cc][p] = 0.f;
      #pragma unroll
      for (int p = 0; p < 8; p++) {
        const int irow = ig * 8 + p;
        const int fb = irow * 128 + jj * 2;
        const int sxx = (irow * 8 + (jj >> 3)) & 15;
        const int k0 = fb & 15;
        const float4 v0 = *reinterpret_cast<const float4*>(&tile[((fb & ~15) | (k0 ^ sxx)) * 4]);
        const float4 v1 = *reinterpret_cast<const float4*>(&tile[((fb & ~15) | ((k0 + 1) ^ sxx)) * 4]);
        const float e[8] = {v0.x, v0.y, v0.z, v0.w, v1.x, v1.y, v1.z, v1.w};
        #pragma unroll
        for (int cc = 0; cc < 4; cc++) {
          const int c = ch * 4 + cc;
          #pragma unroll
          for (int k = 0; k < 8; k++) acc[cc][p] += e[k] * swt[c * 8 + k];
        }
      }
      #pragma unroll
      for (int cc = 0; cc < 4; cc++) {
        const int c = ch * 4 + cc;
        short8 o;
        #pragma unroll
        for (int p = 0; p < 8; p++) o[p] = f2b(acc[cc][p]);
        *reinterpret_cast<short8*>(outp + (size_t)c * PLANE + (size_t)(j0 + jj) * NN + i0 + ig * 8) = o;
      }
    }
  }
}

// fallback single transposed gtconv (c2T) when workspace is too small for 4 buffers
__global__ __launch_bounds__(256) void gtconv_one(const float* __restrict__ A, const float* __restrict__ sw,
                                                  __hip_bfloat16* __restrict__ oT) {
  __shared__ float Als[32][33][9];
  __shared__ float swl[8][8];
  int t = threadIdx.x;
  if (t < 64) swl[t >> 3][t & 7] = sw[t];
  int i0 = blockIdx.y * 32, j0 = blockIdx.x * 32;
  #pragma unroll
  for (int q = 0; q < 8; q++) {
    int fi = t + q * 256;
    int e4 = fi & 1, jj = (fi >> 1) & 31, ii = fi >> 6;
    const float4 v = *reinterpret_cast<const float4*>(A + (((size_t)(i0 + ii) * NN + (j0 + jj)) << 3) + e4 * 4);
    float* dst = &Als[ii][jj][e4 * 4];
    dst[0] = v.x; dst[1] = v.y; dst[2] = v.z; dst[3] = v.w;
  }
  __syncthreads();
  #pragma unroll
  for (int q = 0; q < 4; q++) {
    int pos = t + q * 256;
    int r = pos >> 5, s = pos & 31;
    float e[8];
    #pragma unroll
    for (int k = 0; k < 8; k++) e[k] = Als[s][r][k];
    size_t base = (size_t)(j0 + r) * NN + (i0 + s);
    #pragma unroll
    for (int c = 0; c < 8; c++) {
      float v1 = 0.f;
      #pragma unroll
      for (int k = 0; k < 8; k++) v1 += e[k] * swl[c][k];
      oT[(size_t)c * PLANE + base] = __float2bfloat16(v1);
    }
  }
}

// ---------------------------------------------------------------------------
// m97-faithful 128x128x64 bf16 GEMM: 4 waves (2x2, wave tile 64x64),
// single-buffer 32KB LDS, global_load_lds w16 (linear dest + involution-
// swizzled source; XOR read swizzle -> 0 conflicts), simple 2-barrier loop.
// ~164 regs => 3 blocks/CU; co-resident blocks hide stage drain (m114).
// C output in bf16; col-sum partials from exact fp32 accumulators.
// ---------------------------------------------------------------------------
#define GBM 128
#define GBK 64
template<int CPB, int PARTIALS>
__global__ __launch_bounds__(256, 3) void gemm8(const short* __restrict__ Ag0, const short* __restrict__ Bg0,
                                                short* __restrict__ C, float* __restrict__ degp) {
  __shared__ short lds[16384];          // 32KB: A [0..8191] | B [8192..16383]
  __shared__ float colred[2][128];
  const int t = threadIdx.x;
  const int lane = t & 63, w = t >> 6;
  const int wr = w >> 1, wc = w & 1;    // 2 x 2 wave grid; wave tile 64(M) x 64(N)
  const int m0 = blockIdx.y * GBM, n0 = blockIdx.x * GBM;
  const short* Abase = Ag0 + (size_t)blockIdx.z * CPB * PLANE;
  const short* Bbase = Bg0 + (size_t)blockIdx.z * CPB * PLANE;
  const int NT = CPB * 32;

  const int lrow = t >> 3;              // 0..31 staging row within quarter
  const int lk8  = t & 7;               // 16B chunk id
  const int fr = lane & 15, fk = (lane >> 4) * 8;

  f32x4 acc[4][4] = {};

  auto STAGE = [&](int tt) {
    const int k0 = (tt & 31) * GBK;
    const short* Ag = Abase + (size_t)(tt >> 5) * PLANE;
    const short* Bg = Bbase + (size_t)(tt >> 5) * PLANE;
    #pragma unroll
    for (int q = 0; q < 4; q++) {
      const int row = q * 32 + lrow;
      const int ksrc = ((lk8 ^ (row & 7)) * 8);
      short* la = &lds[q * 2048 + w * 512];
      short* lb = &lds[8192 + q * 2048 + w * 512];
      gload16(Ag + (size_t)(m0 + row) * NN + k0 + ksrc, la);
      gload16(Bg + (size_t)(n0 + row) * NN + k0 + ksrc, lb);
    }
  };

  for (int tt = 0; tt < NT; ++tt) {
    STAGE(tt);
    asm volatile("s_waitcnt vmcnt(0)" ::: "memory");
    __builtin_amdgcn_sched_barrier(0);
    __builtin_amdgcn_s_barrier();                      // tile complete in LDS
    __builtin_amdgcn_sched_barrier(0);

    #pragma unroll
    for (int kx = 0; kx < 2; kx++) {
      short8 af[4], bf[4];
      #pragma unroll
      for (int m = 0; m < 4; m++) {
        const int row = wr * 64 + m * 16 + fr;
        const int sw8 = (row & 7) * 8;
        af[m] = *reinterpret_cast<const short8*>(&lds[row * 64 + ((kx * 32 + fk) ^ sw8)]);
      }
      #pragma unroll
      for (int n = 0; n < 4; n++) {
        const int row = wc * 64 + n * 16 + fr;
        const int sw8 = (row & 7) * 8;
        bf[n] = *reinterpret_cast<const short8*>(&lds[8192 + row * 64 + ((kx * 32 + fk) ^ sw8)]);
      }
      __builtin_amdgcn_s_setprio(1);
      #pragma unroll
      for (int m = 0; m < 4; m++)
        #pragma unroll
        for (int n = 0; n < 4; n++)
          acc[m][n] = __builtin_amdgcn_mfma_f32_16x16x32_bf16(af[m], bf[n], acc[m][n], 0, 0, 0);
      __builtin_amdgcn_s_setprio(0);
    }
    __builtin_amdgcn_sched_barrier(0);
    __builtin_amdgcn_s_barrier();                      // consumption done -> next STAGE safe
    __builtin_amdgcn_sched_barrier(0);
  }

  short* Cg = C + (size_t)blockIdx.z * PLANE;
  const int orow = (lane >> 4) * 4, ocol = lane & 15;
  #pragma unroll
  for (int m = 0; m < 4; m++)
    #pragma unroll
    for (int n = 0; n < 4; n++) {
      const int gr = m0 + wr * 64 + m * 16 + orow;
      const int gc = n0 + wc * 64 + n * 16 + ocol;
      #pragma unroll
      for (int j = 0; j < 4; j++)
        Cg[(size_t)(gr + j) * NN + gc] = f2b(acc[m][n][j]);
    }

  if (PARTIALS) {
    #pragma unroll
    for (int n = 0; n < 4; n++) {
      float s = 0.f;
      #pragma unroll
      for (int m = 0; m < 4; m++)
        #pragma unroll
        for (int j = 0; j < 4; j++) s += acc[m][n][j];
      s += __shfl_xor(s, 16);
      s += __shfl_xor(s, 32);
      if (lane < 16) colred[wr][wc * 64 + n * 16 + lane] = s;
    }
    __syncthreads();
    if (t < 128) {
      float s = colred[0][t] + colred[1][t];
      degp[((size_t)blockIdx.z * 16 + blockIdx.y) * NN + n0 + t] = s;
    }
  }
}

// ---------------------------------------------------------------------------
// deg[c][j] = sum of 16 block partials - diag(bf16); invert
// ---------------------------------------------------------------------------
__global__ __launch_bounds__(256) void reduce_inv(const float* __restrict__ degp, const short* __restrict__ Hb,
                                                  float* __restrict__ deginv) {
  int idx = blockIdx.x * 256 + threadIdx.x;   // 8*2048
  int c = idx >> 11, j = idx & (NN - 1);
  float s = 0.f;
  #pragma unroll
  for (int tb = 0; tb < 16; tb++) s += degp[((size_t)c * 16 + tb) * NN + j];
  s -= b2f(Hb[(size_t)c * PLANE + (size_t)j * NN + j]);
  deginv[idx] = (s == 0.f) ? 0.f : 1.f / s;
}

// ---------------------------------------------------------------------------
// Hn(bf16) = (i==j ? 0 : Hb * deginv[c][j]); 8 elems/thread, bf16 in/out
// ---------------------------------------------------------------------------
__global__ __launch_bounds__(256) void normalize_cast(const short* __restrict__ Hb, const float* __restrict__ deginv,
                                                      short* __restrict__ Hn) {
  size_t idx = (size_t)blockIdx.x * 256 + threadIdx.x;
  size_t e0 = idx * 8;
  int c = (int)(e0 >> 22);
  size_t rem = e0 & (PLANE - 1);
  int i = (int)(rem >> 11), j0 = (int)(rem & (NN - 1));
  const short8 hv = *reinterpret_cast<const short8*>(Hb + e0);
  const float4 d0 = *reinterpret_cast<const float4*>(deginv + c * NN + j0);
  const float4 d1 = *reinterpret_cast<const float4*>(deginv + c * NN + j0 + 4);
  const float dk[8] = {d0.x, d0.y, d0.z, d0.w, d1.x, d1.y, d1.z, d1.w};
  float v[8];
  #pragma unroll
  for (int k = 0; k < 8; k++) v[k] = b2f(hv[k]) * dk[k];
  int dd = i - j0;
  if (dd >= 0 && dd < 8) v[dd] = 0.f;
  short8 o;
  #pragma unroll
  for (int k = 0; k < 8; k++) o[k] = f2b(v[k]);
  *reinterpret_cast<short8*>(Hn + e0) = o;
}

// ---------------------------------------------------------------------------
// out[i][j] = (1/16) * sum_{p<4} (Mp[i][j] + Mp[j][i]); Mp in bf16
// ---------------------------------------------------------------------------
__global__ __launch_bounds__(256) void final_sym4(const short* __restrict__ M, float* __restrict__ out) {
  __shared__ short tl[64][65];
  int t = threadIdx.x;
  int i0 = blockIdx.y * 64, j0 = blockIdx.x * 64;
  int r0 = t >> 6, cl = t & 63;
  float acc[16];
  #pragma unroll
  for (int q = 0; q < 16; q++) acc[q] = 0.f;
  for (int p = 0; p < 4; p++) {
    const short* Mp = M + (size_t)p * PLANE;
    __syncthreads();
    #pragma unroll
    for (int q = 0; q < 16; q++) {
      int rr = r0 + q * 4;
      tl[rr][cl] = Mp[(size_t)(j0 + rr) * NN + i0 + cl];
    }
    __syncthreads();
    #pragma unroll
    for (int q = 0; q < 16; q++) {
      int rr = r0 + q * 4;
      acc[q] += b2f(Mp[(size_t)(i0 + rr) * NN + j0 + cl]) + b2f(tl[cl][rr]);
    }
  }
  #pragma unroll
  for (int q = 0; q < 16; q++) {
    int rr = r0 + q * 4;
    out[(size_t)(i0 + rr) * NN + j0 + cl] = acc[q] * (1.0f / 16.0f);
  }
}

// ---------------------------------------------------------------------------
extern "C" void kernel_launch(void* const* d_in, const int* in_sizes, int n_in,
                              void* d_out, int out_size, void* d_ws, size_t ws_size,
                              hipStream_t stream) {
  const float* A    = (const float*)d_in[0];
  const float* w1_0 = (const float*)d_in[1];
  const float* w2_0 = (const float*)d_in[2];
  const float* w_1  = (const float*)d_in[3];
  const float* w_2  = (const float*)d_in[4];
  float* out = (float*)d_out;

  char* w = (char*)d_ws;
  float* sw     = (float*)w;                                  // 256 f
  float* degp   = (float*)(w + (1 << 17));                    // 8*16*2048 f = 1MB
  float* deginv = (float*)(w + (1 << 17) + (1 << 21));        // 16K f
  const size_t BSZ = (size_t)NC * PLANE * sizeof(short);      // 64MB per bf16 stack
  short* B0 = (short*)(w + (4u << 20));                       // a  / Hn / Hn2
  short* B1 = (short*)((char*)B0 + BSZ);                      // bT (/ c2T in fallback)
  short* B2 = (short*)((char*)B1 + BSZ);                      // c1T
  const size_t need4 = (4u << 20) + 5 * BSZ;                  // 4 inputs + bf16 H
  const bool fused4 = ws_size >= need4;
  short* B3 = (short*)((char*)B2 + BSZ);                      // c2T (fused path only)
  short* HH = fused4 ? (short*)((char*)B3 + BSZ) : (short*)((char*)B2 + BSZ);  // bf16 H / M planes

  dim3 blk(256), blkg(512);
  dim3 gfuse(NN / 64, NN / 32);
  dim3 gconv(64, 64);
  dim3 ggemm(16, 16, 8);
  dim3 ggemm4(16, 16, 4);

  softmax_w_k<<<1, blk, 0, stream>>>(w1_0, w2_0, w_1, w_2, sw);
  if (fused4) {
    gtconv_fused<1><<<gfuse, blkg, 0, stream>>>(A, sw, B0, B1, B2, B3);
  } else {
    gtconv_fused<0><<<gfuse, blkg, 0, stream>>>(A, sw, B0, B1, B2, B3);
  }

  gemm8<1, 1><<<ggemm, blk, 0, stream>>>(B0, B1, HH, degp);           // H1 = a @ b (bf16), + col partials
  reduce_inv<<<64, blk, 0, stream>>>(degp, HH, deginv);
  normalize_cast<<<16384, blk, 0, stream>>>(HH, deginv, B0);          // Hn -> B0
  if (!fused4) {
    gtconv_one<<<gconv, blk, 0, stream>>>(A, sw + 192, (__hip_bfloat16*)B1);  // c2T -> B1
  }

  gemm8<1, 1><<<ggemm, blk, 0, stream>>>(B0, B2, HH, degp);           // H2 = Hn @ c1 (bf16), + partials
  reduce_inv<<<64, blk, 0, stream>>>(degp, HH, deginv);
  normalize_cast<<<16384, blk, 0, stream>>>(HH, deginv, B0);          // Hn2 -> B0

  short* Bc2 = fused4 ? B3 : B1;
  gemm8<2, 0><<<ggemm4, blk, 0, stream>>>(B0, Bc2, HH, degp);         // M[z] = sum_{c in pair z} Hn2[c] @ c2[c]
  final_sym4<<<dim3(32, 32), blk, 0, stream>>>(HH, out);
}

// Round 16
// 585.614 us; speedup vs baseline: 1.3525x; 1.0106x over previous
//
#include <hip/hip_runtime.h>
#include <hip/hip_bf16.h>

using short8 = __attribute__((ext_vector_type(8))) short;
using f32x4  = __attribute__((ext_vector_type(4))) float;

#define NN 2048
#define NC 8
static const size_t PLANE = (size_t)NN * NN;

__device__ __forceinline__ void gload16(const void* g, void* l) {
  __builtin_amdgcn_global_load_lds((const __attribute__((address_space(1))) unsigned int*)g,
                                   (__attribute__((address_space(3))) unsigned int*)l, 16, 0, 0);
}

__device__ __forceinline__ float b2f(short s) {
  unsigned int u = ((unsigned int)(unsigned short)s) << 16;
  float f; __builtin_memcpy(&f, &u, 4); return f;
}
__device__ __forceinline__ short f2b(float f) {
  __hip_bfloat16 hb = __float2bfloat16(f);
  return *reinterpret_cast<short*>(&hb);
}

// ---------------------------------------------------------------------------
// softmax over E=8 for 4 weight tensors [8c][8e] -> sw[4][8][8]
// ---------------------------------------------------------------------------
__global__ __launch_bounds__(256) void softmax_w_k(const float* __restrict__ w0, const float* __restrict__ w1,
                                                   const float* __restrict__ w2, const float* __restrict__ w3,
                                                   float* __restrict__ sw) {
  int t = threadIdx.x;
  const float* srcs[4] = {w0, w1, w2, w3};
  float v = srcs[t >> 6][t & 63];
  float m = v;
  #pragma unroll
  for (int d = 1; d < 8; d <<= 1) m = fmaxf(m, __shfl_xor(m, d, 8));
  float ex = __expf(v - m);
  float s = ex;
  #pragma unroll
  for (int d = 1; d < 8; d <<= 1) s += __shfl_xor(s, d, 8);
  sw[t] = ex / s;
}

// ---------------------------------------------------------------------------
// Fused gtconv: one pass over A [N,N,8] -> a (row-major), bT, c1T, (c2T).
// ---------------------------------------------------------------------------
template<int W4>
__global__ __launch_bounds__(512) void gtconv_fused(const float* __restrict__ A, const float* __restrict__ sw,
                                                    short* __restrict__ a, short* __restrict__ bT,
                                                    short* __restrict__ c1T, short* __restrict__ c2T) {
  __shared__ float tile[16384];     // 64 KB: [i 0..31][j 0..63][e 0..7] swizzled per 16B chunk
  __shared__ float swl[256];
  const int t = threadIdx.x;
  const int i0 = blockIdx.y * 32, j0 = blockIdx.x * 64;
  if (t < 256) swl[t] = sw[t];

  const float* Abase = A + ((size_t)i0 * NN + j0) * 8;
  #pragma unroll
  for (int q = 0; q < 8; q++) {
    const int d = q * 512 + t;
    const int s = (d & ~15) | ((d ^ (d >> 4)) & 15);
    const int row = s >> 7, fc = s & 127;
    gload16(Abase + (size_t)row * (NN * 8) + fc * 4, &tile[(q * 512 + (t & ~63)) * 4]);
  }
  asm volatile("s_waitcnt vmcnt(0)" ::: "memory");
  __syncthreads();

  // ---- row-major pass: tensor 0 ('a') ----
  {
    const int ch = t & 1, jg = (t >> 1) & 7, ii = t >> 4;
    const int sxx = (ii * 8 + jg) & 15;
    const int fb = ii * 128 + jg * 16;
    float acc[4][8];
    #pragma unroll
    for (int cc = 0; cc < 4; cc++)
      #pragma unroll
      for (int p = 0; p < 8; p++) acc[cc][p] = 0.f;
    #pragma unroll
    for (int p = 0; p < 8; p++) {
      const int k0 = p * 2;
      const float4 v0 = *reinterpret_cast<const float4*>(&tile[((fb & ~15) | (k0 ^ sxx)) * 4]);
      const float4 v1 = *reinterpret_cast<const float4*>(&tile[((fb & ~15) | ((k0 + 1) ^ sxx)) * 4]);
      const float e[8] = {v0.x, v0.y, v0.z, v0.w, v1.x, v1.y, v1.z, v1.w};
      #pragma unroll
      for (int cc = 0; cc < 4; cc++) {
        const int c = ch * 4 + cc;
        #pragma unroll
        for (int k = 0; k < 8; k++) acc[cc][p] += e[k] * swl[c * 8 + k];
      }
    }
    #pragma unroll
    for (int cc = 0; cc < 4; cc++) {
      const int c = ch * 4 + cc;
      short8 o;
      #pragma unroll
      for (int p = 0; p < 8; p++) o[p] = f2b(acc[cc][p]);
      *reinterpret_cast<short8*>(a + (size_t)c * PLANE + (size_t)(i0 + ii) * NN + j0 + jg * 8) = o;
    }
  }

  // ---- transposed passes: bT, c1T, (c2T) ----
  {
    const int ch = t & 1, ig = (t >> 1) & 3, jj = t >> 3;
    const int NT_OUT = W4 ? 3 : 2;
    short* outs[3] = {bT, c1T, c2T};
    #pragma unroll
    for (int T = 0; T < NT_OUT; T++) {
      short* outp = outs[T];
      const float* swt = &swl[(T + 1) * 64];
      float acc[4][8];
      #pragma unroll
      for (int cc = 0; cc < 4; cc++)
        #pragma unroll
        for (int p = 0; p < 8; p++) acc[cc][p] = 0.f;
      #pragma unroll
      for (int p = 0; p < 8; p++) {
        const int irow = ig * 8 + p;
        const int fb = irow * 128 + jj * 2;
        const int sxx = (irow * 8 + (jj >> 3)) & 15;
        const int k0 = fb & 15;
        const float4 v0 = *reinterpret_cast<const float4*>(&tile[((fb & ~15) | (k0 ^ sxx)) * 4]);
        const float4 v1 = *reinterpret_cast<const float4*>(&tile[((fb & ~15) | ((k0 + 1) ^ sxx)) * 4]);
        const float e[8] = {v0.x, v0.y, v0.z, v0.w, v1.x, v1.y, v1.z, v1.w};
        #pragma unroll
        for (int cc = 0; cc < 4; cc++) {
          const int c = ch * 4 + cc;
          #pragma unroll
          for (int k = 0; k < 8; k++) acc[cc][p] += e[k] * swt[c * 8 + k];
        }
      }
      #pragma unroll
      for (int cc = 0; cc < 4; cc++) {
        const int c = ch * 4 + cc;
        short8 o;
        #pragma unroll
        for (int p = 0; p < 8; p++) o[p] = f2b(acc[cc][p]);
        *reinterpret_cast<short8*>(outp + (size_t)c * PLANE + (size_t)(j0 + jj) * NN + i0 + ig * 8) = o;
      }
    }
  }
}

// fallback single transposed gtconv (c2T) when workspace is too small for 4 buffers
__global__ __launch_bounds__(256) void gtconv_one(const float* __restrict__ A, const float* __restrict__ sw,
                                                  __hip_bfloat16* __restrict__ oT) {
  __shared__ float Als[32][33][9];
  __shared__ float swl[8][8];
  int t = threadIdx.x;
  if (t < 64) swl[t >> 3][t & 7] = sw[t];
  int i0 = blockIdx.y * 32, j0 = blockIdx.x * 32;
  #pragma unroll
  for (int q = 0; q < 8; q++) {
    int fi = t + q * 256;
    int e4 = fi & 1, jj = (fi >> 1) & 31, ii = fi >> 6;
    const float4 v = *reinterpret_cast<const float4*>(A + (((size_t)(i0 + ii) * NN + (j0 + jj)) << 3) + e4 * 4);
    float* dst = &Als[ii][jj][e4 * 4];
    dst[0] = v.x; dst[1] = v.y; dst[2] = v.z; dst[3] = v.w;
  }
  __syncthreads();
  #pragma unroll
  for (int q = 0; q < 4; q++) {
    int pos = t + q * 256;
    int r = pos >> 5, s = pos & 31;
    float e[8];
    #pragma unroll
    for (int k = 0; k < 8; k++) e[k] = Als[s][r][k];
    size_t base = (size_t)(j0 + r) * NN + (i0 + s);
    #pragma unroll
    for (int c = 0; c < 8; c++) {
      float v1 = 0.f;
      #pragma unroll
      for (int k = 0; k < 8; k++) v1 += e[k] * swl[c][k];
      oT[(size_t)c * PLANE + base] = __float2bfloat16(v1);
    }
  }
}

// ---------------------------------------------------------------------------
// m97-faithful 128x128x64 bf16 GEMM: 4 waves (2x2, wave tile 64x64),
// single-buffer 32KB LDS, global_load_lds w16 (linear dest + involution-
// swizzled source; XOR read swizzle -> 0 conflicts), simple 2-barrier loop.
// 64 VGPR + 64 AGPR = 128 regs -> 4 blocks/CU (launch_bounds(256,4));
// co-resident blocks hide stage drain (m114). C output bf16.
// ---------------------------------------------------------------------------
#define GBM 128
#define GBK 64
template<int CPB, int PARTIALS>
__global__ __launch_bounds__(256, 4) void gemm8(const short* __restrict__ Ag0, const short* __restrict__ Bg0,
                                                short* __restrict__ C, float* __restrict__ degp) {
  __shared__ short lds[16384];          // 32KB: A [0..8191] | B [8192..16383]
  __shared__ float colred[2][128];
  const int t = threadIdx.x;
  const int lane = t & 63, w = t >> 6;
  const int wr = w >> 1, wc = w & 1;    // 2 x 2 wave grid; wave tile 64(M) x 64(N)
  const int m0 = blockIdx.y * GBM, n0 = blockIdx.x * GBM;
  const short* Abase = Ag0 + (size_t)blockIdx.z * CPB * PLANE;
  const short* Bbase = Bg0 + (size_t)blockIdx.z * CPB * PLANE;
  const int NT = CPB * 32;

  const int lrow = t >> 3;              // 0..31 staging row within quarter
  const int lk8  = t & 7;               // 16B chunk id
  const int fr = lane & 15, fk = (lane >> 4) * 8;

  f32x4 acc[4][4] = {};

  auto STAGE = [&](int tt) {
    const int k0 = (tt & 31) * GBK;
    const short* Ag = Abase + (size_t)(tt >> 5) * PLANE;
    const short* Bg = Bbase + (size_t)(tt >> 5) * PLANE;
    #pragma unroll
    for (int q = 0; q < 4; q++) {
      const int row = q * 32 + lrow;
      const int ksrc = ((lk8 ^ (row & 7)) * 8);
      short* la = &lds[q * 2048 + w * 512];
      short* lb = &lds[8192 + q * 2048 + w * 512];
      gload16(Ag + (size_t)(m0 + row) * NN + k0 + ksrc, la);
      gload16(Bg + (size_t)(n0 + row) * NN + k0 + ksrc, lb);
    }
  };

  for (int tt = 0; tt < NT; ++tt) {
    STAGE(tt);
    asm volatile("s_waitcnt vmcnt(0)" ::: "memory");
    __builtin_amdgcn_sched_barrier(0);
    __builtin_amdgcn_s_barrier();                      // tile complete in LDS
    __builtin_amdgcn_sched_barrier(0);

    #pragma unroll
    for (int kx = 0; kx < 2; kx++) {
      short8 af[4], bf[4];
      #pragma unroll
      for (int m = 0; m < 4; m++) {
        const int row = wr * 64 + m * 16 + fr;
        const int sw8 = (row & 7) * 8;
        af[m] = *reinterpret_cast<const short8*>(&lds[row * 64 + ((kx * 32 + fk) ^ sw8)]);
      }
      #pragma unroll
      for (int n = 0; n < 4; n++) {
        const int row = wc * 64 + n * 16 + fr;
        const int sw8 = (row & 7) * 8;
        bf[n] = *reinterpret_cast<const short8*>(&lds[8192 + row * 64 + ((kx * 32 + fk) ^ sw8)]);
      }
      __builtin_amdgcn_s_setprio(1);
      #pragma unroll
      for (int m = 0; m < 4; m++)
        #pragma unroll
        for (int n = 0; n < 4; n++)
          acc[m][n] = __builtin_amdgcn_mfma_f32_16x16x32_bf16(af[m], bf[n], acc[m][n], 0, 0, 0);
      __builtin_amdgcn_s_setprio(0);
    }
    __builtin_amdgcn_sched_barrier(0);
    __builtin_amdgcn_s_barrier();                      // consumption done -> next STAGE safe
    __builtin_amdgcn_sched_barrier(0);
  }

  short* Cg = C + (size_t)blockIdx.z * PLANE;
  const int orow = (lane >> 4) * 4, ocol = lane & 15;
  #pragma unroll
  for (int m = 0; m < 4; m++)
    #pragma unroll
    for (int n = 0; n < 4; n++) {
      const int gr = m0 + wr * 64 + m * 16 + orow;
      const int gc = n0 + wc * 64 + n * 16 + ocol;
      #pragma unroll
      for (int j = 0; j < 4; j++)
        Cg[(size_t)(gr + j) * NN + gc] = f2b(acc[m][n][j]);
    }

  if (PARTIALS) {
    #pragma unroll
    for (int n = 0; n < 4; n++) {
      float s = 0.f;
      #pragma unroll
      for (int m = 0; m < 4; m++)
        #pragma unroll
        for (int j = 0; j < 4; j++) s += acc[m][n][j];
      s += __shfl_xor(s, 16);
      s += __shfl_xor(s, 32);
      if (lane < 16) colred[wr][wc * 64 + n * 16 + lane] = s;
    }
    __syncthreads();
    if (t < 128) {
      float s = colred[0][t] + colred[1][t];
      degp[((size_t)blockIdx.z * 16 + blockIdx.y) * NN + n0 + t] = s;
    }
  }
}

// ---------------------------------------------------------------------------
// deg[c][j] = sum of 16 block partials - diag(bf16); invert
// ---------------------------------------------------------------------------
__global__ __launch_bounds__(256) void reduce_inv(const float* __restrict__ degp, const short* __restrict__ Hb,
                                                  float* __restrict__ deginv) {
  int idx = blockIdx.x * 256 + threadIdx.x;   // 8*2048
  int c = idx >> 11, j = idx & (NN - 1);
  float s = 0.f;
  #pragma unroll
  for (int tb = 0; tb < 16; tb++) s += degp[((size_t)c * 16 + tb) * NN + j];
  s -= b2f(Hb[(size_t)c * PLANE + (size_t)j * NN + j]);
  deginv[idx] = (s == 0.f) ? 0.f : 1.f / s;
}

// ---------------------------------------------------------------------------
// Hn(bf16) = (i==j ? 0 : Hb * deginv[c][j]); 8 elems/thread, bf16 in/out
// ---------------------------------------------------------------------------
__global__ __launch_bounds__(256) void normalize_cast(const short* __restrict__ Hb, const float* __restrict__ deginv,
                                                      short* __restrict__ Hn) {
  size_t idx = (size_t)blockIdx.x * 256 + threadIdx.x;
  size_t e0 = idx * 8;
  int c = (int)(e0 >> 22);
  size_t rem = e0 & (PLANE - 1);
  int i = (int)(rem >> 11), j0 = (int)(rem & (NN - 1));
  const short8 hv = *reinterpret_cast<const short8*>(Hb + e0);
  const float4 d0 = *reinterpret_cast<const float4*>(deginv + c * NN + j0);
  const float4 d1 = *reinterpret_cast<const float4*>(deginv + c * NN + j0 + 4);
  const float dk[8] = {d0.x, d0.y, d0.z, d0.w, d1.x, d1.y, d1.z, d1.w};
  float v[8];
  #pragma unroll
  for (int k = 0; k < 8; k++) v[k] = b2f(hv[k]) * dk[k];
  int dd = i - j0;
  if (dd >= 0 && dd < 8) v[dd] = 0.f;
  short8 o;
  #pragma unroll
  for (int k = 0; k < 8; k++) o[k] = f2b(v[k]);
  *reinterpret_cast<short8*>(Hn + e0) = o;
}

// ---------------------------------------------------------------------------
// out[i][j] = (1/16) * sum_{p<4} (Mp[i][j] + Mp[j][i]); Mp in bf16
// ---------------------------------------------------------------------------
__global__ __launch_bounds__(256) void final_sym4(const short* __restrict__ M, float* __restrict__ out) {
  __shared__ short tl[64][65];
  int t = threadIdx.x;
  int i0 = blockIdx.y * 64, j0 = blockIdx.x * 64;
  int r0 = t >> 6, cl = t & 63;
  float acc[16];
  #pragma unroll
  for (int q = 0; q < 16; q++) acc[q] = 0.f;
  for (int p = 0; p < 4; p++) {
    const short* Mp = M + (size_t)p * PLANE;
    __syncthreads();
    #pragma unroll
    for (int q = 0; q < 16; q++) {
      int rr = r0 + q * 4;
      tl[rr][cl] = Mp[(size_t)(j0 + rr) * NN + i0 + cl];
    }
    __syncthreads();
    #pragma unroll
    for (int q = 0; q < 16; q++) {
      int rr = r0 + q * 4;
      acc[q] += b2f(Mp[(size_t)(i0 + rr) * NN + j0 + cl]) + b2f(tl[cl][rr]);
    }
  }
  #pragma unroll
  for (int q = 0; q < 16; q++) {
    int rr = r0 + q * 4;
    out[(size_t)(i0 + rr) * NN + j0 + cl] = acc[q] * (1.0f / 16.0f);
  }
}

// ---------------------------------------------------------------------------
extern "C" void kernel_launch(void* const* d_in, const int* in_sizes, int n_in,
                              void* d_out, int out_size, void* d_ws, size_t ws_size,
                              hipStream_t stream) {
  const float* A    = (const float*)d_in[0];
  const float* w1_0 = (const float*)d_in[1];
  const float* w2_0 = (const float*)d_in[2];
  const float* w_1  = (const float*)d_in[3];
  const float* w_2  = (const float*)d_in[4];
  float* out = (float*)d_out;

  char* w = (char*)d_ws;
  float* sw     = (float*)w;                                  // 256 f
  float* degp   = (float*)(w + (1 << 17));                    // 8*16*2048 f = 1MB
  float* deginv = (float*)(w + (1 << 17) + (1 << 21));        // 16K f
  const size_t BSZ = (size_t)NC * PLANE * sizeof(short);      // 64MB per bf16 stack
  short* B0 = (short*)(w + (4u << 20));                       // a  / Hn / Hn2
  short* B1 = (short*)((char*)B0 + BSZ);                      // bT (/ c2T in fallback)
  short* B2 = (short*)((char*)B1 + BSZ);                      // c1T
  const size_t need4 = (4u << 20) + 5 * BSZ;                  // 4 inputs + bf16 H
  const bool fused4 = ws_size >= need4;
  short* B3 = (short*)((char*)B2 + BSZ);                      // c2T (fused path only)
  short* HH = fused4 ? (short*)((char*)B3 + BSZ) : (short*)((char*)B2 + BSZ);  // bf16 H / M planes

  dim3 blk(256), blkg(512);
  dim3 gfuse(NN / 64, NN / 32);
  dim3 gconv(64, 64);
  dim3 ggemm(16, 16, 8);
  dim3 ggemm4(16, 16, 4);

  softmax_w_k<<<1, blk, 0, stream>>>(w1_0, w2_0, w_1, w_2, sw);
  if (fused4) {
    gtconv_fused<1><<<gfuse, blkg, 0, stream>>>(A, sw, B0, B1, B2, B3);
  } else {
    gtconv_fused<0><<<gfuse, blkg, 0, stream>>>(A, sw, B0, B1, B2, B3);
  }

  gemm8<1, 1><<<ggemm, blk, 0, stream>>>(B0, B1, HH, degp);           // H1 = a @ b (bf16), + col partials
  reduce_inv<<<64, blk, 0, stream>>>(degp, HH, deginv);
  normalize_cast<<<16384, blk, 0, stream>>>(HH, deginv, B0);          // Hn -> B0
  if (!fused4) {
    gtconv_one<<<gconv, blk, 0, stream>>>(A, sw + 192, (__hip_bfloat16*)B1);  // c2T -> B1
  }

  gemm8<1, 1><<<ggemm, blk, 0, stream>>>(B0, B2, HH, degp);           // H2 = Hn @ c1 (bf16), + partials
  reduce_inv<<<64, blk, 0, stream>>>(degp, HH, deginv);
  normalize_cast<<<16384, blk, 0, stream>>>(HH, deginv, B0);          // Hn2 -> B0

  short* Bc2 = fused4 ? B3 : B1;
  gemm8<2, 0><<<ggemm4, blk, 0, stream>>>(B0, Bc2, HH, degp);         // M[z] = sum_{c in pair z} Hn2[c] @ c2[c]
  final_sym4<<<dim3(32, 32), blk, 0, stream>>>(HH, out);
}

// Round 17
// 581.883 us; speedup vs baseline: 1.3612x; 1.0064x over previous
//
#include <hip/hip_runtime.h>
#include <hip/hip_bf16.h>

using short8 = __attribute__((ext_vector_type(8))) short;
using f32x4  = __attribute__((ext_vector_type(4))) float;

#define NN 2048
#define NC 8
static const size_t PLANE = (size_t)NN * NN;

__device__ __forceinline__ void gload16(const void* g, void* l) {
  __builtin_amdgcn_global_load_lds((const __attribute__((address_space(1))) unsigned int*)g,
                                   (__attribute__((address_space(3))) unsigned int*)l, 16, 0, 0);
}

__device__ __forceinline__ float b2f(short s) {
  unsigned int u = ((unsigned int)(unsigned short)s) << 16;
  float f; __builtin_memcpy(&f, &u, 4); return f;
}
__device__ __forceinline__ short f2b(float f) {
  __hip_bfloat16 hb = __float2bfloat16(f);
  return *reinterpret_cast<short*>(&hb);
}

// ---------------------------------------------------------------------------
// softmax over E=8 for 4 weight tensors [8c][8e] -> sw[4][8][8]
// ---------------------------------------------------------------------------
__global__ __launch_bounds__(256) void softmax_w_k(const float* __restrict__ w0, const float* __restrict__ w1,
                                                   const float* __restrict__ w2, const float* __restrict__ w3,
                                                   float* __restrict__ sw) {
  int t = threadIdx.x;
  const float* srcs[4] = {w0, w1, w2, w3};
  float v = srcs[t >> 6][t & 63];
  float m = v;
  #pragma unroll
  for (int d = 1; d < 8; d <<= 1) m = fmaxf(m, __shfl_xor(m, d, 8));
  float ex = __expf(v - m);
  float s = ex;
  #pragma unroll
  for (int d = 1; d < 8; d <<= 1) s += __shfl_xor(s, d, 8);
  sw[t] = ex / s;
}

// ---------------------------------------------------------------------------
// Fused gtconv: one pass over A [N,N,8] -> a (row-major), bT, c1T, (c2T).
// ---------------------------------------------------------------------------
template<int W4>
__global__ __launch_bounds__(512) void gtconv_fused(const float* __restrict__ A, const float* __restrict__ sw,
                                                    short* __restrict__ a, short* __restrict__ bT,
                                                    short* __restrict__ c1T, short* __restrict__ c2T) {
  __shared__ float tile[16384];     // 64 KB: [i 0..31][j 0..63][e 0..7] swizzled per 16B chunk
  __shared__ float swl[256];
  const int t = threadIdx.x;
  const int i0 = blockIdx.y * 32, j0 = blockIdx.x * 64;
  if (t < 256) swl[t] = sw[t];

  const float* Abase = A + ((size_t)i0 * NN + j0) * 8;
  #pragma unroll
  for (int q = 0; q < 8; q++) {
    const int d = q * 512 + t;
    const int s = (d & ~15) | ((d ^ (d >> 4)) & 15);
    const int row = s >> 7, fc = s & 127;
    gload16(Abase + (size_t)row * (NN * 8) + fc * 4, &tile[(q * 512 + (t & ~63)) * 4]);
  }
  asm volatile("s_waitcnt vmcnt(0)" ::: "memory");
  __syncthreads();

  // ---- row-major pass: tensor 0 ('a') ----
  {
    const int ch = t & 1, jg = (t >> 1) & 7, ii = t >> 4;
    const int sxx = (ii * 8 + jg) & 15;
    const int fb = ii * 128 + jg * 16;
    float acc[4][8];
    #pragma unroll
    for (int cc = 0; cc < 4; cc++)
      #pragma unroll
      for (int p = 0; p < 8; p++) acc[cc][p] = 0.f;
    #pragma unroll
    for (int p = 0; p < 8; p++) {
      const int k0 = p * 2;
      const float4 v0 = *reinterpret_cast<const float4*>(&tile[((fb & ~15) | (k0 ^ sxx)) * 4]);
      const float4 v1 = *reinterpret_cast<const float4*>(&tile[((fb & ~15) | ((k0 + 1) ^ sxx)) * 4]);
      const float e[8] = {v0.x, v0.y, v0.z, v0.w, v1.x, v1.y, v1.z, v1.w};
      #pragma unroll
      for (int cc = 0; cc < 4; cc++) {
        const int c = ch * 4 + cc;
        #pragma unroll
        for (int k = 0; k < 8; k++) acc[cc][p] += e[k] * swl[c * 8 + k];
      }
    }
    #pragma unroll
    for (int cc = 0; cc < 4; cc++) {
      const int c = ch * 4 + cc;
      short8 o;
      #pragma unroll
      for (int p = 0; p < 8; p++) o[p] = f2b(acc[cc][p]);
      *reinterpret_cast<short8*>(a + (size_t)c * PLANE + (size_t)(i0 + ii) * NN + j0 + jg * 8) = o;
    }
  }

  // ---- transposed passes: bT, c1T, (c2T) ----
  {
    const int ch = t & 1, ig = (t >> 1) & 3, jj = t >> 3;
    const int NT_OUT = W4 ? 3 : 2;
    short* outs[3] = {bT, c1T, c2T};
    #pragma unroll
    for (int T = 0; T < NT_OUT; T++) {
      short* outp = outs[T];
      const float* swt = &swl[(T + 1) * 64];
      float acc[4][8];
      #pragma unroll
      for (int cc = 0; cc < 4; cc++)
        #pragma unroll
        for (int p = 0; p < 8; p++) acc[cc][p] = 0.f;
      #pragma unroll
      for (int p = 0; p < 8; p++) {
        const int irow = ig * 8 + p;
        const int fb = irow * 128 + jj * 2;
        const int sxx = (irow * 8 + (jj >> 3)) & 15;
        const int k0 = fb & 15;
        const float4 v0 = *reinterpret_cast<const float4*>(&tile[((fb & ~15) | (k0 ^ sxx)) * 4]);
        const float4 v1 = *reinterpret_cast<const float4*>(&tile[((fb & ~15) | ((k0 + 1) ^ sxx)) * 4]);
        const float e[8] = {v0.x, v0.y, v0.z, v0.w, v1.x, v1.y, v1.z, v1.w};
        #pragma unroll
        for (int cc = 0; cc < 4; cc++) {
          const int c = ch * 4 + cc;
          #pragma unroll
          for (int k = 0; k < 8; k++) acc[cc][p] += e[k] * swt[c * 8 + k];
        }
      }
      #pragma unroll
      for (int cc = 0; cc < 4; cc++) {
        const int c = ch * 4 + cc;
        short8 o;
        #pragma unroll
        for (int p = 0; p < 8; p++) o[p] = f2b(acc[cc][p]);
        *reinterpret_cast<short8*>(outp + (size_t)c * PLANE + (size_t)(j0 + jj) * NN + i0 + ig * 8) = o;
      }
    }
  }
}

// fallback single transposed gtconv (c2T) when workspace is too small for 4 buffers
__global__ __launch_bounds__(256) void gtconv_one(const float* __restrict__ A, const float* __restrict__ sw,
                                                  __hip_bfloat16* __restrict__ oT) {
  __shared__ float Als[32][33][9];
  __shared__ float swl[8][8];
  int t = threadIdx.x;
  if (t < 64) swl[t >> 3][t & 7] = sw[t];
  int i0 = blockIdx.y * 32, j0 = blockIdx.x * 32;
  #pragma unroll
  for (int q = 0; q < 8; q++) {
    int fi = t + q * 256;
    int e4 = fi & 1, jj = (fi >> 1) & 31, ii = fi >> 6;
    const float4 v = *reinterpret_cast<const float4*>(A + (((size_t)(i0 + ii) * NN + (j0 + jj)) << 3) + e4 * 4);
    float* dst = &Als[ii][jj][e4 * 4];
    dst[0] = v.x; dst[1] = v.y; dst[2] = v.z; dst[3] = v.w;
  }
  __syncthreads();
  #pragma unroll
  for (int q = 0; q < 4; q++) {
    int pos = t + q * 256;
    int r = pos >> 5, s = pos & 31;
    float e[8];
    #pragma unroll
    for (int k = 0; k < 8; k++) e[k] = Als[s][r][k];
    size_t base = (size_t)(j0 + r) * NN + (i0 + s);
    #pragma unroll
    for (int c = 0; c < 8; c++) {
      float v1 = 0.f;
      #pragma unroll
      for (int k = 0; k < 8; k++) v1 += e[k] * swl[c][k];
      oT[(size_t)c * PLANE + base] = __float2bfloat16(v1);
    }
  }
}

// ---------------------------------------------------------------------------
// m97-faithful 128x128x64 bf16 GEMM: 4 waves (2x2, wave tile 64x64),
// single-buffer 32KB LDS, global_load_lds w16 (linear dest + involution-
// swizzled source; XOR read swizzle -> 0 conflicts), simple 2-barrier loop.
// 3 blocks/CU co-residency hides stage drain (m114). C output bf16.
// XCD-chunked tile remap (T1): dispatch-consecutive blocks on one XCD cover
// contiguous (by) rows -> A-panel reuse localizes to that XCD's L2.
// ---------------------------------------------------------------------------
#define GBM 128
#define GBK 64
template<int CPB, int PARTIALS>
__global__ __launch_bounds__(256, 3) void gemm8(const short* __restrict__ Ag0, const short* __restrict__ Bg0,
                                                short* __restrict__ C, float* __restrict__ degp) {
  __shared__ short lds[16384];          // 32KB: A [0..8191] | B [8192..16383]
  __shared__ float colred[2][128];
  const int t = threadIdx.x;
  const int lane = t & 63, w = t >> 6;
  const int wr = w >> 1, wc = w & 1;    // 2 x 2 wave grid; wave tile 64(M) x 64(N)

  // XCD-chunked bijective remap within the 256-block z-slice (256 % 8 == 0):
  // dispatch order round-robins XCDs; tile = (flat%8)*32 + flat/8 gives each
  // XCD a contiguous run of 32 tiles = 2 complete A-panel rows.
  const int flat = blockIdx.y * 16 + blockIdx.x;
  const int swz  = (flat & 7) * 32 + (flat >> 3);
  const int bx = swz & 15, by = swz >> 4;

  const int m0 = by * GBM, n0 = bx * GBM;
  const short* Abase = Ag0 + (size_t)blockIdx.z * CPB * PLANE;
  const short* Bbase = Bg0 + (size_t)blockIdx.z * CPB * PLANE;
  const int NT = CPB * 32;

  const int lrow = t >> 3;              // 0..31 staging row within quarter
  const int lk8  = t & 7;               // 16B chunk id
  const int fr = lane & 15, fk = (lane >> 4) * 8;

  f32x4 acc[4][4] = {};

  auto STAGE = [&](int tt) {
    const int k0 = (tt & 31) * GBK;
    const short* Ag = Abase + (size_t)(tt >> 5) * PLANE;
    const short* Bg = Bbase + (size_t)(tt >> 5) * PLANE;
    #pragma unroll
    for (int q = 0; q < 4; q++) {
      const int row = q * 32 + lrow;
      const int ksrc = ((lk8 ^ (row & 7)) * 8);
      short* la = &lds[q * 2048 + w * 512];
      short* lb = &lds[8192 + q * 2048 + w * 512];
      gload16(Ag + (size_t)(m0 + row) * NN + k0 + ksrc, la);
      gload16(Bg + (size_t)(n0 + row) * NN + k0 + ksrc, lb);
    }
  };

  for (int tt = 0; tt < NT; ++tt) {
    STAGE(tt);
    asm volatile("s_waitcnt vmcnt(0)" ::: "memory");
    __builtin_amdgcn_sched_barrier(0);
    __builtin_amdgcn_s_barrier();                      // tile complete in LDS
    __builtin_amdgcn_sched_barrier(0);

    #pragma unroll
    for (int kx = 0; kx < 2; kx++) {
      short8 af[4], bf[4];
      #pragma unroll
      for (int m = 0; m < 4; m++) {
        const int row = wr * 64 + m * 16 + fr;
        const int sw8 = (row & 7) * 8;
        af[m] = *reinterpret_cast<const short8*>(&lds[row * 64 + ((kx * 32 + fk) ^ sw8)]);
      }
      #pragma unroll
      for (int n = 0; n < 4; n++) {
        const int row = wc * 64 + n * 16 + fr;
        const int sw8 = (row & 7) * 8;
        bf[n] = *reinterpret_cast<const short8*>(&lds[8192 + row * 64 + ((kx * 32 + fk) ^ sw8)]);
      }
      __builtin_amdgcn_s_setprio(1);
      #pragma unroll
      for (int m = 0; m < 4; m++)
        #pragma unroll
        for (int n = 0; n < 4; n++)
          acc[m][n] = __builtin_amdgcn_mfma_f32_16x16x32_bf16(af[m], bf[n], acc[m][n], 0, 0, 0);
      __builtin_amdgcn_s_setprio(0);
    }
    __builtin_amdgcn_sched_barrier(0);
    __builtin_amdgcn_s_barrier();                      // consumption done -> next STAGE safe
    __builtin_amdgcn_sched_barrier(0);
  }

  short* Cg = C + (size_t)blockIdx.z * PLANE;
  const int orow = (lane >> 4) * 4, ocol = lane & 15;
  #pragma unroll
  for (int m = 0; m < 4; m++)
    #pragma unroll
    for (int n = 0; n < 4; n++) {
      const int gr = m0 + wr * 64 + m * 16 + orow;
      const int gc = n0 + wc * 64 + n * 16 + ocol;
      #pragma unroll
      for (int j = 0; j < 4; j++)
        Cg[(size_t)(gr + j) * NN + gc] = f2b(acc[m][n][j]);
    }

  if (PARTIALS) {
    #pragma unroll
    for (int n = 0; n < 4; n++) {
      float s = 0.f;
      #pragma unroll
      for (int m = 0; m < 4; m++)
        #pragma unroll
        for (int j = 0; j < 4; j++) s += acc[m][n][j];
      s += __shfl_xor(s, 16);
      s += __shfl_xor(s, 32);
      if (lane < 16) colred[wr][wc * 64 + n * 16 + lane] = s;
    }
    __syncthreads();
    if (t < 128) {
      float s = colred[0][t] + colred[1][t];
      degp[((size_t)blockIdx.z * 16 + by) * NN + n0 + t] = s;
    }
  }
}

// ---------------------------------------------------------------------------
// deg[c][j] = sum of 16 block partials - diag(bf16); invert
// ---------------------------------------------------------------------------
__global__ __launch_bounds__(256) void reduce_inv(const float* __restrict__ degp, const short* __restrict__ Hb,
                                                  float* __restrict__ deginv) {
  int idx = blockIdx.x * 256 + threadIdx.x;   // 8*2048
  int c = idx >> 11, j = idx & (NN - 1);
  float s = 0.f;
  #pragma unroll
  for (int tb = 0; tb < 16; tb++) s += degp[((size_t)c * 16 + tb) * NN + j];
  s -= b2f(Hb[(size_t)c * PLANE + (size_t)j * NN + j]);
  deginv[idx] = (s == 0.f) ? 0.f : 1.f / s;
}

// ---------------------------------------------------------------------------
// Hn(bf16) = (i==j ? 0 : Hb * deginv[c][j]); 8 elems/thread, bf16 in/out
// ---------------------------------------------------------------------------
__global__ __launch_bounds__(256) void normalize_cast(const short* __restrict__ Hb, const float* __restrict__ deginv,
                                                      short* __restrict__ Hn) {
  size_t idx = (size_t)blockIdx.x * 256 + threadIdx.x;
  size_t e0 = idx * 8;
  int c = (int)(e0 >> 22);
  size_t rem = e0 & (PLANE - 1);
  int i = (int)(rem >> 11), j0 = (int)(rem & (NN - 1));
  const short8 hv = *reinterpret_cast<const short8*>(Hb + e0);
  const float4 d0 = *reinterpret_cast<const float4*>(deginv + c * NN + j0);
  const float4 d1 = *reinterpret_cast<const float4*>(deginv + c * NN + j0 + 4);
  const float dk[8] = {d0.x, d0.y, d0.z, d0.w, d1.x, d1.y, d1.z, d1.w};
  float v[8];
  #pragma unroll
  for (int k = 0; k < 8; k++) v[k] = b2f(hv[k]) * dk[k];
  int dd = i - j0;
  if (dd >= 0 && dd < 8) v[dd] = 0.f;
  short8 o;
  #pragma unroll
  for (int k = 0; k < 8; k++) o[k] = f2b(v[k]);
  *reinterpret_cast<short8*>(Hn + e0) = o;
}

// ---------------------------------------------------------------------------
// out[i][j] = (1/16) * sum_{p<4} (Mp[i][j] + Mp[j][i]); Mp in bf16
// ---------------------------------------------------------------------------
__global__ __launch_bounds__(256) void final_sym4(const short* __restrict__ M, float* __restrict__ out) {
  __shared__ short tl[64][65];
  int t = threadIdx.x;
  int i0 = blockIdx.y * 64, j0 = blockIdx.x * 64;
  int r0 = t >> 6, cl = t & 63;
  float acc[16];
  #pragma unroll
  for (int q = 0; q < 16; q++) acc[q] = 0.f;
  for (int p = 0; p < 4; p++) {
    const short* Mp = M + (size_t)p * PLANE;
    __syncthreads();
    #pragma unroll
    for (int q = 0; q < 16; q++) {
      int rr = r0 + q * 4;
      tl[rr][cl] = Mp[(size_t)(j0 + rr) * NN + i0 + cl];
    }
    __syncthreads();
    #pragma unroll
    for (int q = 0; q < 16; q++) {
      int rr = r0 + q * 4;
      acc[q] += b2f(Mp[(size_t)(i0 + rr) * NN + j0 + cl]) + b2f(tl[cl][rr]);
    }
  }
  #pragma unroll
  for (int q = 0; q < 16; q++) {
    int rr = r0 + q * 4;
    out[(size_t)(i0 + rr) * NN + j0 + cl] = acc[q] * (1.0f / 16.0f);
  }
}

// ---------------------------------------------------------------------------
extern "C" void kernel_launch(void* const* d_in, const int* in_sizes, int n_in,
                              void* d_out, int out_size, void* d_ws, size_t ws_size,
                              hipStream_t stream) {
  const float* A    = (const float*)d_in[0];
  const float* w1_0 = (const float*)d_in[1];
  const float* w2_0 = (const float*)d_in[2];
  const float* w_1  = (const float*)d_in[3];
  const float* w_2  = (const float*)d_in[4];
  float* out = (float*)d_out;

  char* w = (char*)d_ws;
  float* sw     = (float*)w;                                  // 256 f
  float* degp   = (float*)(w + (1 << 17));                    // 8*16*2048 f = 1MB
  float* deginv = (float*)(w + (1 << 17) + (1 << 21));        // 16K f
  const size_t BSZ = (size_t)NC * PLANE * sizeof(short);      // 64MB per bf16 stack
  short* B0 = (short*)(w + (4u << 20));                       // a  / Hn / Hn2
  short* B1 = (short*)((char*)B0 + BSZ);                      // bT (/ c2T in fallback)
  short* B2 = (short*)((char*)B1 + BSZ);                      // c1T
  const size_t need4 = (4u << 20) + 5 * BSZ;                  // 4 inputs + bf16 H
  const bool fused4 = ws_size >= need4;
  short* B3 = (short*)((char*)B2 + BSZ);                      // c2T (fused path only)
  short* HH = fused4 ? (short*)((char*)B3 + BSZ) : (short*)((char*)B2 + BSZ);  // bf16 H / M planes

  dim3 blk(256), blkg(512);
  dim3 gfuse(NN / 64, NN / 32);
  dim3 gconv(64, 64);
  dim3 ggemm(16, 16, 8);
  dim3 ggemm4(16, 16, 4);

  softmax_w_k<<<1, blk, 0, stream>>>(w1_0, w2_0, w_1, w_2, sw);
  if (fused4) {
    gtconv_fused<1><<<gfuse, blkg, 0, stream>>>(A, sw, B0, B1, B2, B3);
  } else {
    gtconv_fused<0><<<gfuse, blkg, 0, stream>>>(A, sw, B0, B1, B2, B3);
  }

  gemm8<1, 1><<<ggemm, blk, 0, stream>>>(B0, B1, HH, degp);           // H1 = a @ b (bf16), + col partials
  reduce_inv<<<64, blk, 0, stream>>>(degp, HH, deginv);
  normalize_cast<<<16384, blk, 0, stream>>>(HH, deginv, B0);          // Hn -> B0
  if (!fused4) {
    gtconv_one<<<gconv, blk, 0, stream>>>(A, sw + 192, (__hip_bfloat16*)B1);  // c2T -> B1
  }

  gemm8<1, 1><<<ggemm, blk, 0, stream>>>(B0, B2, HH, degp);           // H2 = Hn @ c1 (bf16), + partials
  reduce_inv<<<64, blk, 0, stream>>>(degp, HH, deginv);
  normalize_cast<<<16384, blk, 0, stream>>>(HH, deginv, B0);          // Hn2 -> B0

  short* Bc2 = fused4 ? B3 : B1;
  gemm8<2, 0><<<ggemm4, blk, 0, stream>>>(B0, Bc2, HH, degp);         // M[z] = sum_{c in pair z} Hn2[c] @ c2[c]
  final_sym4<<<dim3(32, 32), blk, 0, stream>>>(HH, out);
}